// Round 3
// baseline (20833.923 us; speedup 1.0000x reference)
//
#include <hip/hip_runtime.h>

// MMGCRN fp32 baseline.
// B=64, T=12, N=1024, HOR=12, D_IN=1, D_OUT=1, RNN=64, E=8, K=3,
// MEM_N=10, MEM_D=32, DEC=96, YCOV=1.
constexpr int B_ = 64, T_ = 12, NN = 1024, HOR_ = 12;

// ---------------------------------------------------------------------------
// C = A (M x Kd) @ B (Ncol x Kd)^T, row-major, 64x64 tile, 4x4/thread.
// Used for: logits_enc = emb @ emb^T (Kd=8), A_dec = WE @ WE^T (Kd=512).
__global__ void gemm_nt_kernel(const float* __restrict__ A, const float* __restrict__ Bm,
                               float* __restrict__ C, int Ncol, int Kd) {
  __shared__ float As[16][68];
  __shared__ float Bs[16][68];
  const int bm = blockIdx.y * 64, bn = blockIdx.x * 64;
  const int tid = threadIdx.x;
  const int tx = tid & 15, ty = tid >> 4;
  float acc[4][4] = {};
  for (int k0 = 0; k0 < Kd; k0 += 16) {
#pragma unroll
    for (int r = 0; r < 4; ++r) {
      const int m = (tid >> 4) + r * 16;
      const int kk = tid & 15;
      const int k = k0 + kk;
      As[kk][m] = (k < Kd) ? A[(size_t)(bm + m) * Kd + k] : 0.f;
      Bs[kk][m] = (k < Kd) ? Bm[(size_t)(bn + m) * Kd + k] : 0.f;
    }
    __syncthreads();
#pragma unroll
    for (int kk = 0; kk < 16; ++kk) {
      float a[4], b[4];
#pragma unroll
      for (int i = 0; i < 4; ++i) a[i] = As[kk][ty * 4 + i];
#pragma unroll
      for (int j = 0; j < 4; ++j) b[j] = Bs[kk][tx * 4 + j];
#pragma unroll
      for (int i = 0; i < 4; ++i)
#pragma unroll
        for (int j = 0; j < 4; ++j) acc[i][j] += a[i] * b[j];
    }
    __syncthreads();
  }
#pragma unroll
  for (int i = 0; i < 4; ++i)
#pragma unroll
    for (int j = 0; j < 4; ++j)
      C[(size_t)(bm + ty * 4 + i) * Ncol + bn + tx * 4 + j] = acc[i][j];
}

// ---------------------------------------------------------------------------
// In-place row-wise softmax(relu(x)) over 1024 columns; 1 block per row.
__global__ void relu_softmax_kernel(float* __restrict__ S) {
  const int row = blockIdx.x;
  float* r = S + (size_t)row * NN;
  const int tid = threadIdx.x;  // 256
  float v[4];
  float mx = 0.f;  // relu output >= 0, so 0 is a valid lower bound for max
#pragma unroll
  for (int j = 0; j < 4; ++j) {
    float xv = fmaxf(r[tid + j * 256], 0.f);
    v[j] = xv;
    mx = fmaxf(mx, xv);
  }
#pragma unroll
  for (int off = 1; off < 64; off <<= 1) mx = fmaxf(mx, __shfl_xor(mx, off));
  __shared__ float sred[4];
  const int wv = tid >> 6;
  if ((tid & 63) == 0) sred[wv] = mx;
  __syncthreads();
  mx = fmaxf(fmaxf(sred[0], sred[1]), fmaxf(sred[2], sred[3]));
  __syncthreads();
  float s = 0.f;
#pragma unroll
  for (int j = 0; j < 4; ++j) { v[j] = expf(v[j] - mx); s += v[j]; }
#pragma unroll
  for (int off = 1; off < 64; off <<= 1) s += __shfl_xor(s, off);
  if ((tid & 63) == 0) sred[wv] = s;
  __syncthreads();
  s = sred[0] + sred[1] + sred[2] + sred[3];
  const float inv = 1.f / s;
#pragma unroll
  for (int j = 0; j < 4; ++j) r[tid + j * 256] = v[j] * inv;
}

// ---------------------------------------------------------------------------
// S2 = 2*S@S - I   (1024^3, NN row-major)
__global__ void cheb_kernel(const float* __restrict__ S, float* __restrict__ S2) {
  __shared__ float As[16][68];
  __shared__ float Bs[16][68];
  const int bm = blockIdx.y * 64, bn = blockIdx.x * 64;
  const int tid = threadIdx.x;
  const int tx = tid & 15, ty = tid >> 4;
  float acc[4][4] = {};
  for (int k0 = 0; k0 < NN; k0 += 16) {
#pragma unroll
    for (int r = 0; r < 4; ++r) {
      const int m = (tid >> 4) + r * 16, kk = tid & 15;
      As[kk][m] = S[(size_t)(bm + m) * NN + k0 + kk];
    }
#pragma unroll
    for (int r = 0; r < 4; ++r) {
      const int kk = (tid >> 6) + r * 4, c = tid & 63;
      Bs[kk][c] = S[(size_t)(k0 + kk) * NN + bn + c];
    }
    __syncthreads();
#pragma unroll
    for (int kk = 0; kk < 16; ++kk) {
      float a[4], b[4];
#pragma unroll
      for (int i = 0; i < 4; ++i) a[i] = As[kk][ty * 4 + i];
#pragma unroll
      for (int j = 0; j < 4; ++j) b[j] = Bs[kk][tx * 4 + j];
#pragma unroll
      for (int i = 0; i < 4; ++i)
#pragma unroll
        for (int j = 0; j < 4; ++j) acc[i][j] += a[i] * b[j];
    }
    __syncthreads();
  }
#pragma unroll
  for (int i = 0; i < 4; ++i) {
    const int row = bm + ty * 4 + i;
#pragma unroll
    for (int j = 0; j < 4; ++j) {
      const int col = bn + tx * 4 + j;
      S2[(size_t)row * NN + col] = 2.f * acc[i][j] - (row == col ? 1.f : 0.f);
    }
  }
}

// ---------------------------------------------------------------------------
// Graph conv, both supports at once:
//   xg slice1 = S1 @ X, xg slice2 = S2 @ X, where X = xg slice0.
// xg layout: (N, B, 3, C) floats, row stride LDR = B*3*C; column j = b*C + c.
template <int C>
__global__ void graph_kernel(const float* __restrict__ S1, const float* __restrict__ S2,
                             float* __restrict__ xg) {
  constexpr int LDR = B_ * 3 * C;
  __shared__ float A1[16][68];
  __shared__ float A2[16][68];
  __shared__ float Xs[16][68];
  const int bn = blockIdx.y * 64;  // node tile
  const int bj = blockIdx.x * 64;  // flat (b,c) tile
  const int tid = threadIdx.x;
  const int tx = tid & 15, ty = tid >> 4;
  float acc1[4][4] = {}, acc2[4][4] = {};
  for (int k0 = 0; k0 < NN; k0 += 16) {
#pragma unroll
    for (int r = 0; r < 4; ++r) {
      const int m = (tid >> 4) + r * 16, kk = tid & 15;
      A1[kk][m] = S1[(size_t)(bn + m) * NN + k0 + kk];
      A2[kk][m] = S2[(size_t)(bn + m) * NN + k0 + kk];
    }
#pragma unroll
    for (int r = 0; r < 4; ++r) {
      const int kk = (tid >> 6) + r * 4, jj = tid & 63;
      const int j = bj + jj;
      const int b = j / C, c = j - b * C;
      Xs[kk][jj] = xg[(size_t)(k0 + kk) * LDR + b * (3 * C) + c];
    }
    __syncthreads();
#pragma unroll
    for (int kk = 0; kk < 16; ++kk) {
      float a1[4], a2[4], xv[4];
#pragma unroll
      for (int i = 0; i < 4; ++i) { a1[i] = A1[kk][ty * 4 + i]; a2[i] = A2[kk][ty * 4 + i]; }
#pragma unroll
      for (int j = 0; j < 4; ++j) xv[j] = Xs[kk][tx * 4 + j];
#pragma unroll
      for (int i = 0; i < 4; ++i)
#pragma unroll
        for (int j = 0; j < 4; ++j) {
          acc1[i][j] += a1[i] * xv[j];
          acc2[i][j] += a2[i] * xv[j];
        }
    }
    __syncthreads();
  }
#pragma unroll
  for (int jj = 0; jj < 4; ++jj) {
    const int j = bj + tx * 4 + jj;
    const int b = j / C, c = j - b * C;
    const size_t coloff = (size_t)b * (3 * C) + c;
#pragma unroll
    for (int i = 0; i < 4; ++i) {
      const size_t rowb = (size_t)(bn + ty * 4 + i) * LDR;
      xg[rowb + coloff + C] = acc1[i][jj];
      xg[rowb + coloff + 2 * C] = acc2[i][jj];
    }
  }
}

// ---------------------------------------------------------------------------
// out = act( A (65536 x KK, contiguous) @ W (KK x NO) + bias )
// ACT: 0=none, 1=sigmoid, 2=tanh
template <int KK, int NO, int ACT>
__global__ void dense_kernel(const float* __restrict__ A, const float* __restrict__ W,
                             const float* __restrict__ bias, float* __restrict__ out) {
  constexpr int NO16 = NO / 16;
  __shared__ float As[16][68];
  __shared__ float Ws[16][NO + 4];
  const int row0 = blockIdx.x * 64;
  const int tid = threadIdx.x;
  const int tx = tid & 15, ty = tid >> 4;
  float acc[4][NO16] = {};
  for (int k0 = 0; k0 < KK; k0 += 16) {
#pragma unroll
    for (int r = 0; r < 4; ++r) {
      const int m = (tid >> 4) + r * 16, kk = tid & 15;
      const int k = k0 + kk;
      As[kk][m] = (k < KK) ? A[(size_t)(row0 + m) * KK + k] : 0.f;
    }
    for (int i = tid; i < 16 * NO; i += 256) {
      const int kk = i / NO, c = i - kk * NO;
      const int k = k0 + kk;
      Ws[kk][c] = (k < KK) ? W[(size_t)k * NO + c] : 0.f;
    }
    __syncthreads();
#pragma unroll
    for (int kk = 0; kk < 16; ++kk) {
      float a[4];
#pragma unroll
      for (int i = 0; i < 4; ++i) a[i] = As[kk][ty * 4 + i];
#pragma unroll
      for (int j = 0; j < NO16; ++j) {
        const float wv = Ws[kk][tx * NO16 + j];
#pragma unroll
        for (int i = 0; i < 4; ++i) acc[i][j] += a[i] * wv;
      }
    }
    __syncthreads();
  }
#pragma unroll
  for (int j = 0; j < NO16; ++j) {
    const int c = tx * NO16 + j;
    const float bv = bias[c];
#pragma unroll
    for (int i = 0; i < 4; ++i) {
      float v = acc[i][j] + bv;
      if (ACT == 1) v = 1.f / (1.f + expf(-v));
      else if (ACT == 2) v = tanhf(v);
      out[(size_t)(row0 + ty * 4 + i) * NO + c] = v;
    }
  }
}

// ---------------------------------------------------------------------------
// Elementwise builders. One thread per (n,b); idx = n*B + b.
__global__ void build_enc_kernel(const float* __restrict__ x, const float* __restrict__ h,
                                 float* __restrict__ xg, int t) {
  const int idx = blockIdx.x * 256 + threadIdx.x;
  const int n = idx >> 6, b = idx & 63;
  float* dst = xg + (size_t)idx * 195;
  dst[0] = x[((size_t)b * T_ + t) * NN + n];
  const float* hp = h + (size_t)idx * 64;
#pragma unroll
  for (int i = 0; i < 64; ++i) dst[1 + i] = hp[i];
}

__global__ void cand_enc_kernel(const float* __restrict__ zr, const float* __restrict__ h,
                                float* __restrict__ xg) {
  const int idx = blockIdx.x * 256 + threadIdx.x;
  float* dst = xg + (size_t)idx * 195 + 1;
  const float* z = zr + (size_t)idx * 128;
  const float* hp = h + (size_t)idx * 64;
#pragma unroll
  for (int i = 0; i < 64; ++i) dst[i] = z[i] * hp[i];
}

template <int H>
__global__ void combine_kernel(const float* __restrict__ zr, const float* __restrict__ hcb,
                               float* __restrict__ h) {
  const int e = blockIdx.x * 256 + threadIdx.x;  // < N*B*H
  const int idx = e / H, i = e - idx * H;
  const float r = zr[(size_t)idx * (2 * H) + H + i];
  const float hcv = hcb[e];
  const float hv = h[e];
  h[e] = r * hv + (1.f - r) * hcv;
}

// attention + prototype + W_E, fused. One thread per (n,b).
__global__ void attn_kernel(const float* __restrict__ h, const float* __restrict__ Wq,
                            const float* __restrict__ Mem, const float* __restrict__ FCE,
                            float* __restrict__ proto, float* __restrict__ WE) {
  __shared__ float sWq[64 * 32];
  __shared__ float sM[10 * 32];
  __shared__ float sF[32 * 8];
  const int tid = threadIdx.x;
  for (int i = tid; i < 64 * 32; i += 256) sWq[i] = Wq[i];
  for (int i = tid; i < 10 * 32; i += 256) sM[i] = Mem[i];
  for (int i = tid; i < 32 * 8; i += 256) sF[i] = FCE[i];
  __syncthreads();
  const int idx = blockIdx.x * 256 + tid;
  const float* hp = h + (size_t)idx * 64;
  float q[32] = {};
  for (int i0 = 0; i0 < 16; ++i0) {
    const float4 h4 = *(const float4*)(hp + i0 * 4);
#pragma unroll
    for (int jj = 0; jj < 4; ++jj) {
      const float hv = ((const float*)&h4)[jj];
      const int i = i0 * 4 + jj;
#pragma unroll
      for (int c = 0; c < 32; ++c) q[c] += hv * sWq[i * 32 + c];
    }
  }
  float lg[10];
  float mx = -1e30f;
#pragma unroll
  for (int m = 0; m < 10; ++m) {
    float s = 0.f;
#pragma unroll
    for (int c = 0; c < 32; ++c) s += q[c] * sM[m * 32 + c];
    lg[m] = s;
    mx = fmaxf(mx, s);
  }
  float den = 0.f;
#pragma unroll
  for (int m = 0; m < 10; ++m) { lg[m] = expf(lg[m] - mx); den += lg[m]; }
  const float inv = 1.f / den;
  float p[32] = {};
#pragma unroll
  for (int m = 0; m < 10; ++m) {
    const float a = lg[m] * inv;
#pragma unroll
    for (int c = 0; c < 32; ++c) p[c] += a * sM[m * 32 + c];
  }
  float* pd = proto + (size_t)idx * 32;
#pragma unroll
  for (int c = 0; c < 32; ++c) pd[c] = p[c];
  float* wd = WE + (size_t)idx * 8;  // (n, b*8+e) layout == idx*8+e
#pragma unroll
  for (int e = 0; e < 8; ++e) {
    float s = 0.f;
#pragma unroll
    for (int c = 0; c < 32; ++c) s += p[c] * sF[c * 8 + e];
    wd[e] = s;
  }
}

__global__ void build_h0_kernel(const float* __restrict__ hA, const float* __restrict__ proto,
                                float* __restrict__ hB) {
  const int idx = blockIdx.x * 256 + threadIdx.x;
  float* dst = hB + (size_t)idx * 96;
  const float* s1 = hA + (size_t)idx * 64;
  const float* s2 = proto + (size_t)idx * 32;
#pragma unroll
  for (int i = 0; i < 64; ++i) dst[i] = s1[i];
#pragma unroll
  for (int i = 0; i < 32; ++i) dst[64 + i] = s2[i];
}

__global__ void build_dec_kernel(const float* __restrict__ go, const float* __restrict__ ycov,
                                 const float* __restrict__ hB, float* __restrict__ xg, int t) {
  const int idx = blockIdx.x * 256 + threadIdx.x;
  const int n = idx >> 6, b = idx & 63;
  float* dst = xg + (size_t)idx * 294;
  dst[0] = go[idx];
  dst[1] = ycov[((size_t)b * HOR_ + t) * NN + n];
  const float* hp = hB + (size_t)idx * 96;
#pragma unroll
  for (int i = 0; i < 96; ++i) dst[2 + i] = hp[i];
}

__global__ void cand_dec_kernel(const float* __restrict__ zr, const float* __restrict__ h,
                                float* __restrict__ xg) {
  const int idx = blockIdx.x * 256 + threadIdx.x;
  float* dst = xg + (size_t)idx * 294 + 2;
  const float* z = zr + (size_t)idx * 192;
  const float* hp = h + (size_t)idx * 96;
#pragma unroll
  for (int i = 0; i < 96; ++i) dst[i] = z[i] * hp[i];
}

__global__ void proj_kernel(const float* __restrict__ h, const float* __restrict__ pW,
                            const float* __restrict__ pb, float* __restrict__ go,
                            float* __restrict__ out, int t) {
  __shared__ float sW[96];
  if (threadIdx.x < 96) sW[threadIdx.x] = pW[threadIdx.x];
  __syncthreads();
  const int idx = blockIdx.x * 256 + threadIdx.x;
  const float* hp = h + (size_t)idx * 96;
  float acc = pb[0];
  for (int j0 = 0; j0 < 24; ++j0) {
    const float4 h4 = *(const float4*)(hp + j0 * 4);
    acc += h4.x * sW[j0 * 4] + h4.y * sW[j0 * 4 + 1] + h4.z * sW[j0 * 4 + 2] + h4.w * sW[j0 * 4 + 3];
  }
  go[idx] = acc;
  const int n = idx >> 6, b = idx & 63;
  out[((size_t)b * HOR_ + t) * NN + n] = acc;
}

// ---------------------------------------------------------------------------
extern "C" void kernel_launch(void* const* d_in, const int* in_sizes, int n_in,
                              void* d_out, int out_size, void* d_ws, size_t ws_size,
                              hipStream_t stream) {
  const float* x    = (const float*)d_in[0];
  const float* ycov = (const float*)d_in[1];
  const float* emb  = (const float*)d_in[2];
  const float* egW  = (const float*)d_in[3];
  const float* egb  = (const float*)d_in[4];
  const float* euW  = (const float*)d_in[5];
  const float* eub  = (const float*)d_in[6];
  const float* Mem  = (const float*)d_in[7];
  const float* Wq   = (const float*)d_in[8];
  const float* FCE  = (const float*)d_in[9];
  const float* dgW  = (const float*)d_in[10];
  const float* dgb  = (const float*)d_in[11];
  const float* duW  = (const float*)d_in[12];
  const float* dub  = (const float*)d_in[13];
  const float* pW   = (const float*)d_in[14];
  const float* pb   = (const float*)d_in[15];
  float* out = (float*)d_out;

  float* w = (float*)d_ws;
  auto alloc = [&](size_t nf) { float* p = w; w += nf; return p; };
  float* S1  = alloc((size_t)NN * NN);          // S (enc, then reused for dec)
  float* S2  = alloc((size_t)NN * NN);          // 2S^2 - I
  float* xg  = alloc((size_t)NN * B_ * 294);    // (N,B,3,C) staging, max C=98
  float* zr  = alloc((size_t)NN * B_ * 192);    // gate output, max 2*96
  float* hc  = alloc((size_t)NN * B_ * 96);     // candidate
  float* hA  = alloc((size_t)NN * B_ * 64);     // encoder state
  float* hB  = alloc((size_t)NN * B_ * 96);     // decoder state
  float* go  = alloc((size_t)NN * B_);          // decoder output feedback
  float* proto = alloc((size_t)NN * B_ * 32);
  float* WE  = alloc((size_t)NN * B_ * 8);      // (N, B*8) for S_dec syrk
  (void)ws_size; (void)in_sizes; (void)n_in; (void)out_size;

  const dim3 blk(256);

  // ---- encoder supports ----
  gemm_nt_kernel<<<dim3(16, 16), blk, 0, stream>>>(emb, emb, S1, NN, 8);
  relu_softmax_kernel<<<NN, blk, 0, stream>>>(S1);
  cheb_kernel<<<dim3(16, 16), blk, 0, stream>>>(S1, S2);

  hipMemsetAsync(hA, 0, (size_t)NN * B_ * 64 * sizeof(float), stream);

  // ---- encoder scan ----
  for (int t = 0; t < T_; ++t) {
    build_enc_kernel<<<256, blk, 0, stream>>>(x, hA, xg, t);
    graph_kernel<65><<<dim3(65, 16), blk, 0, stream>>>(S1, S2, xg);
    dense_kernel<195, 128, 1><<<1024, blk, 0, stream>>>(xg, egW, egb, zr);
    cand_enc_kernel<<<256, blk, 0, stream>>>(zr, hA, xg);
    graph_kernel<65><<<dim3(65, 16), blk, 0, stream>>>(S1, S2, xg);
    dense_kernel<195, 64, 2><<<1024, blk, 0, stream>>>(xg, euW, eub, hc);
    combine_kernel<64><<<16384, blk, 0, stream>>>(zr, hc, hA);
  }

  // ---- attention / memory / decoder supports ----
  attn_kernel<<<256, blk, 0, stream>>>(hA, Wq, Mem, FCE, proto, WE);
  gemm_nt_kernel<<<dim3(16, 16), blk, 0, stream>>>(WE, WE, S1, NN, 512);
  relu_softmax_kernel<<<NN, blk, 0, stream>>>(S1);
  cheb_kernel<<<dim3(16, 16), blk, 0, stream>>>(S1, S2);
  build_h0_kernel<<<256, blk, 0, stream>>>(hA, proto, hB);
  hipMemsetAsync(go, 0, (size_t)NN * B_ * sizeof(float), stream);

  // ---- decoder scan ----
  for (int t = 0; t < HOR_; ++t) {
    build_dec_kernel<<<256, blk, 0, stream>>>(go, ycov, hB, xg, t);
    graph_kernel<98><<<dim3(98, 16), blk, 0, stream>>>(S1, S2, xg);
    dense_kernel<294, 192, 1><<<1024, blk, 0, stream>>>(xg, dgW, dgb, zr);
    cand_dec_kernel<<<256, blk, 0, stream>>>(zr, hB, xg);
    graph_kernel<98><<<dim3(98, 16), blk, 0, stream>>>(S1, S2, xg);
    dense_kernel<294, 96, 2><<<1024, blk, 0, stream>>>(xg, duW, dub, hc);
    combine_kernel<96><<<24576, blk, 0, stream>>>(zr, hc, hB);
    proj_kernel<<<256, blk, 0, stream>>>(hB, pW, pb, go, out, t);
  }
}

// Round 4
// 18247.153 us; speedup vs baseline: 1.1418x; 1.1418x over previous
//
#include <hip/hip_runtime.h>
#include <hip/hip_bf16.h>

// MMGCRN: graph convs on MFMA (bf16x3 split = fp32-class accuracy).
// B=64, T=12, N=1024, HOR=12, RNN=64, DEC=96, K=3.
constexpr int B_ = 64, T_ = 12, NN = 1024, HOR_ = 12;

typedef __attribute__((ext_vector_type(8))) short short8;   // 8 bf16 (4 VGPRs)
typedef __attribute__((ext_vector_type(4))) float f32x4;    // MFMA C/D frag

static __device__ inline unsigned short f2bh(float v) {
  __hip_bfloat16 h = __float2bfloat16(v);
  return *reinterpret_cast<unsigned short*>(&h);
}
static __device__ inline float bh2f(unsigned short u) {
  __hip_bfloat16 h = *reinterpret_cast<__hip_bfloat16*>(&u);
  return __bfloat162float(h);
}
static __device__ inline void split_bf16(float v, unsigned short& hi, unsigned short& lo) {
  hi = f2bh(v);
  lo = f2bh(v - bh2f(hi));
}

// ---------------------------------------------------------------------------
// C = A (M x Kd) @ B (Ncol x Kd)^T, row-major, 64x64 tile, 4x4/thread. fp32.
__global__ void gemm_nt_kernel(const float* __restrict__ A, const float* __restrict__ Bm,
                               float* __restrict__ C, int Ncol, int Kd) {
  __shared__ float As[16][68];
  __shared__ float Bs[16][68];
  const int bm = blockIdx.y * 64, bn = blockIdx.x * 64;
  const int tid = threadIdx.x;
  const int tx = tid & 15, ty = tid >> 4;
  float acc[4][4] = {};
  for (int k0 = 0; k0 < Kd; k0 += 16) {
#pragma unroll
    for (int r = 0; r < 4; ++r) {
      const int m = (tid >> 4) + r * 16;
      const int kk = tid & 15;
      const int k = k0 + kk;
      As[kk][m] = (k < Kd) ? A[(size_t)(bm + m) * Kd + k] : 0.f;
      Bs[kk][m] = (k < Kd) ? Bm[(size_t)(bn + m) * Kd + k] : 0.f;
    }
    __syncthreads();
#pragma unroll
    for (int kk = 0; kk < 16; ++kk) {
      float a[4], b[4];
#pragma unroll
      for (int i = 0; i < 4; ++i) a[i] = As[kk][ty * 4 + i];
#pragma unroll
      for (int j = 0; j < 4; ++j) b[j] = Bs[kk][tx * 4 + j];
#pragma unroll
      for (int i = 0; i < 4; ++i)
#pragma unroll
        for (int j = 0; j < 4; ++j) acc[i][j] += a[i] * b[j];
    }
    __syncthreads();
  }
#pragma unroll
  for (int i = 0; i < 4; ++i)
#pragma unroll
    for (int j = 0; j < 4; ++j)
      C[(size_t)(bm + ty * 4 + i) * Ncol + bn + tx * 4 + j] = acc[i][j];
}

// ---------------------------------------------------------------------------
// In-place row softmax(relu(x)) over 1024 cols; also emits bf16 hi/lo split.
__global__ void relu_softmax_kernel(float* __restrict__ S, unsigned short* __restrict__ Sh,
                                    unsigned short* __restrict__ Sl) {
  const int row = blockIdx.x;
  float* r = S + (size_t)row * NN;
  const int tid = threadIdx.x;  // 256
  float v[4];
  float mx = 0.f;
#pragma unroll
  for (int j = 0; j < 4; ++j) {
    float xv = fmaxf(r[tid + j * 256], 0.f);
    v[j] = xv;
    mx = fmaxf(mx, xv);
  }
#pragma unroll
  for (int off = 1; off < 64; off <<= 1) mx = fmaxf(mx, __shfl_xor(mx, off));
  __shared__ float sred[4];
  const int wv = tid >> 6;
  if ((tid & 63) == 0) sred[wv] = mx;
  __syncthreads();
  mx = fmaxf(fmaxf(sred[0], sred[1]), fmaxf(sred[2], sred[3]));
  __syncthreads();
  float s = 0.f;
#pragma unroll
  for (int j = 0; j < 4; ++j) { v[j] = expf(v[j] - mx); s += v[j]; }
#pragma unroll
  for (int off = 1; off < 64; off <<= 1) s += __shfl_xor(s, off);
  if ((tid & 63) == 0) sred[wv] = s;
  __syncthreads();
  s = sred[0] + sred[1] + sred[2] + sred[3];
  const float inv = 1.f / s;
#pragma unroll
  for (int j = 0; j < 4; ++j) {
    const float sv = v[j] * inv;
    const size_t e = (size_t)row * NN + tid + j * 256;
    r[tid + j * 256] = sv;
    unsigned short hi, lo;
    split_bf16(sv, hi, lo);
    Sh[e] = hi;
    Sl[e] = lo;
  }
}

// ---------------------------------------------------------------------------
// S2 = 2*S@S - I, emitted directly as bf16 hi/lo split (no fp32 copy kept).
__global__ void cheb_kernel(const float* __restrict__ S, unsigned short* __restrict__ S2h,
                            unsigned short* __restrict__ S2l) {
  __shared__ float As[16][68];
  __shared__ float Bs[16][68];
  const int bm = blockIdx.y * 64, bn = blockIdx.x * 64;
  const int tid = threadIdx.x;
  const int tx = tid & 15, ty = tid >> 4;
  float acc[4][4] = {};
  for (int k0 = 0; k0 < NN; k0 += 16) {
#pragma unroll
    for (int r = 0; r < 4; ++r) {
      const int m = (tid >> 4) + r * 16, kk = tid & 15;
      As[kk][m] = S[(size_t)(bm + m) * NN + k0 + kk];
    }
#pragma unroll
    for (int r = 0; r < 4; ++r) {
      const int kk = (tid >> 6) + r * 4, c = tid & 63;
      Bs[kk][c] = S[(size_t)(k0 + kk) * NN + bn + c];
    }
    __syncthreads();
#pragma unroll
    for (int kk = 0; kk < 16; ++kk) {
      float a[4], b[4];
#pragma unroll
      for (int i = 0; i < 4; ++i) a[i] = As[kk][ty * 4 + i];
#pragma unroll
      for (int j = 0; j < 4; ++j) b[j] = Bs[kk][tx * 4 + j];
#pragma unroll
      for (int i = 0; i < 4; ++i)
#pragma unroll
        for (int j = 0; j < 4; ++j) acc[i][j] += a[i] * b[j];
    }
    __syncthreads();
  }
#pragma unroll
  for (int i = 0; i < 4; ++i) {
    const int row = bm + ty * 4 + i;
#pragma unroll
    for (int j = 0; j < 4; ++j) {
      const int col = bn + tx * 4 + j;
      const float val = 2.f * acc[i][j] - (row == col ? 1.f : 0.f);
      unsigned short hi, lo;
      split_bf16(val, hi, lo);
      S2h[(size_t)row * NN + col] = hi;
      S2l[(size_t)row * NN + col] = lo;
    }
  }
}

// ---------------------------------------------------------------------------
// XT[j][node] (bf16 hi/lo) = transpose+split of xg slice0 (fp32 strided).
// Grid: (W/64, NN/64), block 256. LDS-tiled so both sides stay coalesced.
template <int C>
__global__ void xt_convert_kernel(const float* __restrict__ xg,
                                  unsigned short* __restrict__ XTh,
                                  unsigned short* __restrict__ XTl) {
  constexpr int LDR = B_ * 3 * C;
  __shared__ float tile[64][65];
  const int bj = blockIdx.x * 64, bn = blockIdx.y * 64;
  const int tid = threadIdx.x;
  {
    const int jl = tid & 63, nq = tid >> 6;
    const int j = bj + jl;
    const int b = j / C, c = j - b * C;
    const size_t base = (size_t)b * (3 * C) + c;
#pragma unroll
    for (int r = 0; r < 16; ++r) {
      const int node = bn + nq + r * 4;
      tile[nq + r * 4][jl] = xg[(size_t)node * LDR + base];
    }
  }
  __syncthreads();
  const int nl = tid & 63, jq = tid >> 6;
#pragma unroll
  for (int r = 0; r < 16; ++r) {
    const int j = bj + jq + r * 4;
    const float v = tile[nl][jq + r * 4];
    unsigned short hi, lo;
    split_bf16(v, hi, lo);
    XTh[(size_t)j * NN + bn + nl] = hi;
    XTl[(size_t)j * NN + bn + nl] = lo;
  }
}

// ---------------------------------------------------------------------------
// Graph conv on MFMA: xg slice1 = S1@X, slice2 = S2@X, bf16x3 split products.
// NT-GEMM: A = S (row-major in k), B^T = XT (row-major in k). LDS-free.
// Block 256 = 4 waves; wave w owns rows [bn+w*16, +16) x cols [bj, bj+64).
template <int C>
__global__ void graph_mfma_kernel(const unsigned short* __restrict__ S1h,
                                  const unsigned short* __restrict__ S1l,
                                  const unsigned short* __restrict__ S2h,
                                  const unsigned short* __restrict__ S2l,
                                  const unsigned short* __restrict__ XTh,
                                  const unsigned short* __restrict__ XTl,
                                  float* __restrict__ xg) {
  constexpr int LDR = B_ * 3 * C;
  const int bj = blockIdx.x * 64;
  const int bn = blockIdx.y * 64;
  const int w = threadIdx.x >> 6;
  const int lane = threadIdx.x & 63;
  const int row = lane & 15, kq = lane >> 4;
  const size_t a_off = (size_t)(bn + w * 16 + row) * NN + kq * 8;
  const size_t b_off = (size_t)(bj + row) * NN + kq * 8;  // + jt*16*NN
  f32x4 acc[2][4] = {};
  for (int k0 = 0; k0 < NN; k0 += 32) {
    const short8 a1h = *(const short8*)(S1h + a_off + k0);
    const short8 a1l = *(const short8*)(S1l + a_off + k0);
    const short8 a2h = *(const short8*)(S2h + a_off + k0);
    const short8 a2l = *(const short8*)(S2l + a_off + k0);
    short8 bh[4], bl[4];
#pragma unroll
    for (int jt = 0; jt < 4; ++jt) {
      bh[jt] = *(const short8*)(XTh + b_off + (size_t)jt * 16 * NN + k0);
      bl[jt] = *(const short8*)(XTl + b_off + (size_t)jt * 16 * NN + k0);
    }
#pragma unroll
    for (int jt = 0; jt < 4; ++jt) {
      acc[0][jt] = __builtin_amdgcn_mfma_f32_16x16x32_bf16(a1h, bh[jt], acc[0][jt], 0, 0, 0);
      acc[0][jt] = __builtin_amdgcn_mfma_f32_16x16x32_bf16(a1h, bl[jt], acc[0][jt], 0, 0, 0);
      acc[0][jt] = __builtin_amdgcn_mfma_f32_16x16x32_bf16(a1l, bh[jt], acc[0][jt], 0, 0, 0);
      acc[1][jt] = __builtin_amdgcn_mfma_f32_16x16x32_bf16(a2h, bh[jt], acc[1][jt], 0, 0, 0);
      acc[1][jt] = __builtin_amdgcn_mfma_f32_16x16x32_bf16(a2h, bl[jt], acc[1][jt], 0, 0, 0);
      acc[1][jt] = __builtin_amdgcn_mfma_f32_16x16x32_bf16(a2l, bh[jt], acc[1][jt], 0, 0, 0);
    }
  }
  // D mapping (m89-verified): col = lane&15, row = (lane>>4)*4 + reg.
  const int node0 = bn + w * 16 + kq * 4;
#pragma unroll
  for (int jt = 0; jt < 4; ++jt) {
    const int j = bj + jt * 16 + row;
    const int b = j / C, c = j - b * C;
    const size_t base = (size_t)b * (3 * C) + c;
#pragma unroll
    for (int r = 0; r < 4; ++r) {
      const size_t rowb = (size_t)(node0 + r) * LDR + base;
      xg[rowb + C] = acc[0][jt][r];
      xg[rowb + 2 * C] = acc[1][jt][r];
    }
  }
}

// ---------------------------------------------------------------------------
// out = act( A (65536 x KK) @ W (KK x NO) + bias ); ACT: 0=none,1=sigmoid,2=tanh
template <int KK, int NO, int ACT>
__global__ void dense_kernel(const float* __restrict__ A, const float* __restrict__ W,
                             const float* __restrict__ bias, float* __restrict__ out) {
  constexpr int NO16 = NO / 16;
  __shared__ float As[16][68];
  __shared__ float Ws[16][NO + 4];
  const int row0 = blockIdx.x * 64;
  const int tid = threadIdx.x;
  const int tx = tid & 15, ty = tid >> 4;
  float acc[4][NO16] = {};
  for (int k0 = 0; k0 < KK; k0 += 16) {
#pragma unroll
    for (int r = 0; r < 4; ++r) {
      const int m = (tid >> 4) + r * 16, kk = tid & 15;
      const int k = k0 + kk;
      As[kk][m] = (k < KK) ? A[(size_t)(row0 + m) * KK + k] : 0.f;
    }
    for (int i = tid; i < 16 * NO; i += 256) {
      const int kk = i / NO, c = i - kk * NO;
      const int k = k0 + kk;
      Ws[kk][c] = (k < KK) ? W[(size_t)k * NO + c] : 0.f;
    }
    __syncthreads();
#pragma unroll
    for (int kk = 0; kk < 16; ++kk) {
      float a[4];
#pragma unroll
      for (int i = 0; i < 4; ++i) a[i] = As[kk][ty * 4 + i];
#pragma unroll
      for (int j = 0; j < NO16; ++j) {
        const float wv = Ws[kk][tx * NO16 + j];
#pragma unroll
        for (int i = 0; i < 4; ++i) acc[i][j] += a[i] * wv;
      }
    }
    __syncthreads();
  }
#pragma unroll
  for (int j = 0; j < NO16; ++j) {
    const int c = tx * NO16 + j;
    const float bv = bias[c];
#pragma unroll
    for (int i = 0; i < 4; ++i) {
      float v = acc[i][j] + bv;
      if (ACT == 1) v = 1.f / (1.f + expf(-v));
      else if (ACT == 2) v = tanhf(v);
      out[(size_t)(row0 + ty * 4 + i) * NO + c] = v;
    }
  }
}

// ---------------------------------------------------------------------------
// Elementwise builders. One thread per (n,b); idx = n*B + b.
__global__ void build_enc_kernel(const float* __restrict__ x, const float* __restrict__ h,
                                 float* __restrict__ xg, int t) {
  const int idx = blockIdx.x * 256 + threadIdx.x;
  const int n = idx >> 6, b = idx & 63;
  float* dst = xg + (size_t)idx * 195;
  dst[0] = x[((size_t)b * T_ + t) * NN + n];
  const float* hp = h + (size_t)idx * 64;
#pragma unroll
  for (int i = 0; i < 64; ++i) dst[1 + i] = hp[i];
}

__global__ void cand_enc_kernel(const float* __restrict__ zr, const float* __restrict__ h,
                                float* __restrict__ xg) {
  const int idx = blockIdx.x * 256 + threadIdx.x;
  float* dst = xg + (size_t)idx * 195 + 1;
  const float* z = zr + (size_t)idx * 128;
  const float* hp = h + (size_t)idx * 64;
#pragma unroll
  for (int i = 0; i < 64; ++i) dst[i] = z[i] * hp[i];
}

template <int H>
__global__ void combine_kernel(const float* __restrict__ zr, const float* __restrict__ hcb,
                               float* __restrict__ h) {
  const int e = blockIdx.x * 256 + threadIdx.x;
  const int idx = e / H, i = e - idx * H;
  const float r = zr[(size_t)idx * (2 * H) + H + i];
  h[e] = r * h[e] + (1.f - r) * hcb[e];
}

__global__ void attn_kernel(const float* __restrict__ h, const float* __restrict__ Wq,
                            const float* __restrict__ Mem, const float* __restrict__ FCE,
                            float* __restrict__ proto, float* __restrict__ WE) {
  __shared__ float sWq[64 * 32];
  __shared__ float sM[10 * 32];
  __shared__ float sF[32 * 8];
  const int tid = threadIdx.x;
  for (int i = tid; i < 64 * 32; i += 256) sWq[i] = Wq[i];
  for (int i = tid; i < 10 * 32; i += 256) sM[i] = Mem[i];
  for (int i = tid; i < 32 * 8; i += 256) sF[i] = FCE[i];
  __syncthreads();
  const int idx = blockIdx.x * 256 + tid;
  const float* hp = h + (size_t)idx * 64;
  float q[32] = {};
  for (int i0 = 0; i0 < 16; ++i0) {
    const float4 h4 = *(const float4*)(hp + i0 * 4);
#pragma unroll
    for (int jj = 0; jj < 4; ++jj) {
      const float hv = ((const float*)&h4)[jj];
      const int i = i0 * 4 + jj;
#pragma unroll
      for (int c = 0; c < 32; ++c) q[c] += hv * sWq[i * 32 + c];
    }
  }
  float lg[10];
  float mx = -1e30f;
#pragma unroll
  for (int m = 0; m < 10; ++m) {
    float s = 0.f;
#pragma unroll
    for (int c = 0; c < 32; ++c) s += q[c] * sM[m * 32 + c];
    lg[m] = s;
    mx = fmaxf(mx, s);
  }
  float den = 0.f;
#pragma unroll
  for (int m = 0; m < 10; ++m) { lg[m] = expf(lg[m] - mx); den += lg[m]; }
  const float inv = 1.f / den;
  float p[32] = {};
#pragma unroll
  for (int m = 0; m < 10; ++m) {
    const float a = lg[m] * inv;
#pragma unroll
    for (int c = 0; c < 32; ++c) p[c] += a * sM[m * 32 + c];
  }
  float* pd = proto + (size_t)idx * 32;
#pragma unroll
  for (int c = 0; c < 32; ++c) pd[c] = p[c];
  float* wd = WE + (size_t)idx * 8;
#pragma unroll
  for (int e = 0; e < 8; ++e) {
    float s = 0.f;
#pragma unroll
    for (int c = 0; c < 32; ++c) s += p[c] * sF[c * 8 + e];
    wd[e] = s;
  }
}

__global__ void build_h0_kernel(const float* __restrict__ hA, const float* __restrict__ proto,
                                float* __restrict__ hB) {
  const int idx = blockIdx.x * 256 + threadIdx.x;
  float* dst = hB + (size_t)idx * 96;
  const float* s1 = hA + (size_t)idx * 64;
  const float* s2 = proto + (size_t)idx * 32;
#pragma unroll
  for (int i = 0; i < 64; ++i) dst[i] = s1[i];
#pragma unroll
  for (int i = 0; i < 32; ++i) dst[64 + i] = s2[i];
}

__global__ void build_dec_kernel(const float* __restrict__ go, const float* __restrict__ ycov,
                                 const float* __restrict__ hB, float* __restrict__ xg, int t) {
  const int idx = blockIdx.x * 256 + threadIdx.x;
  const int n = idx >> 6, b = idx & 63;
  float* dst = xg + (size_t)idx * 294;
  dst[0] = go[idx];
  dst[1] = ycov[((size_t)b * HOR_ + t) * NN + n];
  const float* hp = hB + (size_t)idx * 96;
#pragma unroll
  for (int i = 0; i < 96; ++i) dst[2 + i] = hp[i];
}

__global__ void cand_dec_kernel(const float* __restrict__ zr, const float* __restrict__ h,
                                float* __restrict__ xg) {
  const int idx = blockIdx.x * 256 + threadIdx.x;
  float* dst = xg + (size_t)idx * 294 + 2;
  const float* z = zr + (size_t)idx * 192;
  const float* hp = h + (size_t)idx * 96;
#pragma unroll
  for (int i = 0; i < 96; ++i) dst[i] = z[i] * hp[i];
}

__global__ void proj_kernel(const float* __restrict__ h, const float* __restrict__ pW,
                            const float* __restrict__ pb, float* __restrict__ go,
                            float* __restrict__ out, int t) {
  __shared__ float sW[96];
  if (threadIdx.x < 96) sW[threadIdx.x] = pW[threadIdx.x];
  __syncthreads();
  const int idx = blockIdx.x * 256 + threadIdx.x;
  const float* hp = h + (size_t)idx * 96;
  float acc = pb[0];
  for (int j0 = 0; j0 < 24; ++j0) {
    const float4 h4 = *(const float4*)(hp + j0 * 4);
    acc += h4.x * sW[j0 * 4] + h4.y * sW[j0 * 4 + 1] + h4.z * sW[j0 * 4 + 2] + h4.w * sW[j0 * 4 + 3];
  }
  go[idx] = acc;
  const int n = idx >> 6, b = idx & 63;
  out[((size_t)b * HOR_ + t) * NN + n] = acc;
}

// ---------------------------------------------------------------------------
extern "C" void kernel_launch(void* const* d_in, const int* in_sizes, int n_in,
                              void* d_out, int out_size, void* d_ws, size_t ws_size,
                              hipStream_t stream) {
  const float* x    = (const float*)d_in[0];
  const float* ycov = (const float*)d_in[1];
  const float* emb  = (const float*)d_in[2];
  const float* egW  = (const float*)d_in[3];
  const float* egb  = (const float*)d_in[4];
  const float* euW  = (const float*)d_in[5];
  const float* eub  = (const float*)d_in[6];
  const float* Mem  = (const float*)d_in[7];
  const float* Wq   = (const float*)d_in[8];
  const float* FCE  = (const float*)d_in[9];
  const float* dgW  = (const float*)d_in[10];
  const float* dgb  = (const float*)d_in[11];
  const float* duW  = (const float*)d_in[12];
  const float* dub  = (const float*)d_in[13];
  const float* pW   = (const float*)d_in[14];
  const float* pb   = (const float*)d_in[15];
  float* out = (float*)d_out;

  char* w = (char*)d_ws;
  auto alloc = [&](size_t bytes) {
    void* p = (void*)w;
    w += (bytes + 255) & ~(size_t)255;
    return p;
  };
  float* S1    = (float*)alloc((size_t)NN * NN * 4);
  float* xg    = (float*)alloc((size_t)NN * B_ * 294 * 4);
  float* zr    = (float*)alloc((size_t)NN * B_ * 192 * 4);
  float* hc    = (float*)alloc((size_t)NN * B_ * 96 * 4);
  float* hA    = (float*)alloc((size_t)NN * B_ * 64 * 4);
  float* hB    = (float*)alloc((size_t)NN * B_ * 96 * 4);
  float* go    = (float*)alloc((size_t)NN * B_ * 4);
  float* proto = (float*)alloc((size_t)NN * B_ * 32 * 4);
  float* WE    = (float*)alloc((size_t)NN * B_ * 8 * 4);
  unsigned short* S1h = (unsigned short*)alloc((size_t)NN * NN * 2);
  unsigned short* S1l = (unsigned short*)alloc((size_t)NN * NN * 2);
  unsigned short* S2h = (unsigned short*)alloc((size_t)NN * NN * 2);
  unsigned short* S2l = (unsigned short*)alloc((size_t)NN * NN * 2);
  unsigned short* XTh = (unsigned short*)alloc((size_t)B_ * 98 * NN * 2);
  unsigned short* XTl = (unsigned short*)alloc((size_t)B_ * 98 * NN * 2);
  (void)ws_size; (void)in_sizes; (void)n_in; (void)out_size;

  const dim3 blk(256);

  // ---- encoder supports ----
  gemm_nt_kernel<<<dim3(16, 16), blk, 0, stream>>>(emb, emb, S1, NN, 8);
  relu_softmax_kernel<<<NN, blk, 0, stream>>>(S1, S1h, S1l);
  cheb_kernel<<<dim3(16, 16), blk, 0, stream>>>(S1, S2h, S2l);

  hipMemsetAsync(hA, 0, (size_t)NN * B_ * 64 * sizeof(float), stream);

  // ---- encoder scan ----
  for (int t = 0; t < T_; ++t) {
    build_enc_kernel<<<256, blk, 0, stream>>>(x, hA, xg, t);
    xt_convert_kernel<65><<<dim3(65, 16), blk, 0, stream>>>(xg, XTh, XTl);
    graph_mfma_kernel<65><<<dim3(65, 16), blk, 0, stream>>>(S1h, S1l, S2h, S2l, XTh, XTl, xg);
    dense_kernel<195, 128, 1><<<1024, blk, 0, stream>>>(xg, egW, egb, zr);
    cand_enc_kernel<<<256, blk, 0, stream>>>(zr, hA, xg);
    xt_convert_kernel<65><<<dim3(65, 16), blk, 0, stream>>>(xg, XTh, XTl);
    graph_mfma_kernel<65><<<dim3(65, 16), blk, 0, stream>>>(S1h, S1l, S2h, S2l, XTh, XTl, xg);
    dense_kernel<195, 64, 2><<<1024, blk, 0, stream>>>(xg, euW, eub, hc);
    combine_kernel<64><<<16384, blk, 0, stream>>>(zr, hc, hA);
  }

  // ---- attention / memory / decoder supports ----
  attn_kernel<<<256, blk, 0, stream>>>(hA, Wq, Mem, FCE, proto, WE);
  gemm_nt_kernel<<<dim3(16, 16), blk, 0, stream>>>(WE, WE, S1, NN, 512);
  relu_softmax_kernel<<<NN, blk, 0, stream>>>(S1, S1h, S1l);
  cheb_kernel<<<dim3(16, 16), blk, 0, stream>>>(S1, S2h, S2l);
  build_h0_kernel<<<256, blk, 0, stream>>>(hA, proto, hB);
  hipMemsetAsync(go, 0, (size_t)NN * B_ * sizeof(float), stream);

  // ---- decoder scan ----
  for (int t = 0; t < HOR_; ++t) {
    build_dec_kernel<<<256, blk, 0, stream>>>(go, ycov, hB, xg, t);
    xt_convert_kernel<98><<<dim3(98, 16), blk, 0, stream>>>(xg, XTh, XTl);
    graph_mfma_kernel<98><<<dim3(98, 16), blk, 0, stream>>>(S1h, S1l, S2h, S2l, XTh, XTl, xg);
    dense_kernel<294, 192, 1><<<1024, blk, 0, stream>>>(xg, dgW, dgb, zr);
    cand_dec_kernel<<<256, blk, 0, stream>>>(zr, hB, xg);
    xt_convert_kernel<98><<<dim3(98, 16), blk, 0, stream>>>(xg, XTh, XTl);
    graph_mfma_kernel<98><<<dim3(98, 16), blk, 0, stream>>>(S1h, S1l, S2h, S2l, XTh, XTl, xg);
    dense_kernel<294, 96, 2><<<1024, blk, 0, stream>>>(xg, duW, dub, hc);
    combine_kernel<96><<<24576, blk, 0, stream>>>(zr, hc, hB);
    proj_kernel<<<256, blk, 0, stream>>>(hB, pW, pb, go, out, t);
  }
}

// Round 5
// 10476.120 us; speedup vs baseline: 1.9887x; 1.7418x over previous
//
#include <hip/hip_runtime.h>
#include <hip/hip_bf16.h>

// MMGCRN: graph convs on MFMA (bf16x3 split), m97-style LDS-staged GEMM.
// B=64, T=12, N=1024, HOR=12, RNN=64, DEC=96, K=3.
constexpr int B_ = 64, T_ = 12, NN = 1024, HOR_ = 12;

typedef __attribute__((ext_vector_type(8))) short short8;   // 8 bf16 (4 VGPRs)
typedef __attribute__((ext_vector_type(4))) float f32x4;    // MFMA C/D frag

static __device__ inline unsigned short f2bh(float v) {
  __hip_bfloat16 h = __float2bfloat16(v);
  return *reinterpret_cast<unsigned short*>(&h);
}
static __device__ inline float bh2f(unsigned short u) {
  __hip_bfloat16 h = *reinterpret_cast<__hip_bfloat16*>(&u);
  return __bfloat162float(h);
}
static __device__ inline void split_bf16(float v, unsigned short& hi, unsigned short& lo) {
  hi = f2bh(v);
  lo = f2bh(v - bh2f(hi));
}

// async global->LDS, 16B per lane. LDS dest = uniform base + lane*16 (HW rule).
static __device__ inline void gload_lds16(const unsigned short* g, unsigned short* l) {
  __builtin_amdgcn_global_load_lds(
      (const __attribute__((address_space(1))) unsigned int*)g,
      (__attribute__((address_space(3))) unsigned int*)l, 16, 0, 0);
}

// ---------------------------------------------------------------------------
// C = A (M x Kd) @ B (Ncol x Kd)^T, row-major, 64x64 tile, 4x4/thread. fp32.
__global__ void gemm_nt_kernel(const float* __restrict__ A, const float* __restrict__ Bm,
                               float* __restrict__ C, int Ncol, int Kd) {
  __shared__ float As[16][68];
  __shared__ float Bs[16][68];
  const int bm = blockIdx.y * 64, bn = blockIdx.x * 64;
  const int tid = threadIdx.x;
  const int tx = tid & 15, ty = tid >> 4;
  float acc[4][4] = {};
  for (int k0 = 0; k0 < Kd; k0 += 16) {
#pragma unroll
    for (int r = 0; r < 4; ++r) {
      const int m = (tid >> 4) + r * 16;
      const int kk = tid & 15;
      const int k = k0 + kk;
      As[kk][m] = (k < Kd) ? A[(size_t)(bm + m) * Kd + k] : 0.f;
      Bs[kk][m] = (k < Kd) ? Bm[(size_t)(bn + m) * Kd + k] : 0.f;
    }
    __syncthreads();
#pragma unroll
    for (int kk = 0; kk < 16; ++kk) {
      float a[4], b[4];
#pragma unroll
      for (int i = 0; i < 4; ++i) a[i] = As[kk][ty * 4 + i];
#pragma unroll
      for (int j = 0; j < 4; ++j) b[j] = Bs[kk][tx * 4 + j];
#pragma unroll
      for (int i = 0; i < 4; ++i)
#pragma unroll
        for (int j = 0; j < 4; ++j) acc[i][j] += a[i] * b[j];
    }
    __syncthreads();
  }
#pragma unroll
  for (int i = 0; i < 4; ++i)
#pragma unroll
    for (int j = 0; j < 4; ++j)
      C[(size_t)(bm + ty * 4 + i) * Ncol + bn + tx * 4 + j] = acc[i][j];
}

// ---------------------------------------------------------------------------
// In-place row softmax(relu(x)) over 1024 cols; also emits bf16 hi/lo split.
__global__ void relu_softmax_kernel(float* __restrict__ S, unsigned short* __restrict__ Sh,
                                    unsigned short* __restrict__ Sl) {
  const int row = blockIdx.x;
  float* r = S + (size_t)row * NN;
  const int tid = threadIdx.x;  // 256
  float v[4];
  float mx = 0.f;
#pragma unroll
  for (int j = 0; j < 4; ++j) {
    float xv = fmaxf(r[tid + j * 256], 0.f);
    v[j] = xv;
    mx = fmaxf(mx, xv);
  }
#pragma unroll
  for (int off = 1; off < 64; off <<= 1) mx = fmaxf(mx, __shfl_xor(mx, off));
  __shared__ float sred[4];
  const int wv = tid >> 6;
  if ((tid & 63) == 0) sred[wv] = mx;
  __syncthreads();
  mx = fmaxf(fmaxf(sred[0], sred[1]), fmaxf(sred[2], sred[3]));
  __syncthreads();
  float s = 0.f;
#pragma unroll
  for (int j = 0; j < 4; ++j) { v[j] = expf(v[j] - mx); s += v[j]; }
#pragma unroll
  for (int off = 1; off < 64; off <<= 1) s += __shfl_xor(s, off);
  if ((tid & 63) == 0) sred[wv] = s;
  __syncthreads();
  s = sred[0] + sred[1] + sred[2] + sred[3];
  const float inv = 1.f / s;
#pragma unroll
  for (int j = 0; j < 4; ++j) {
    const float sv = v[j] * inv;
    const size_t e = (size_t)row * NN + tid + j * 256;
    r[tid + j * 256] = sv;
    unsigned short hi, lo;
    split_bf16(sv, hi, lo);
    Sh[e] = hi;
    Sl[e] = lo;
  }
}

// ---------------------------------------------------------------------------
// S2 = 2*S@S - I, emitted directly as bf16 hi/lo split.
__global__ void cheb_kernel(const float* __restrict__ S, unsigned short* __restrict__ S2h,
                            unsigned short* __restrict__ S2l) {
  __shared__ float As[16][68];
  __shared__ float Bs[16][68];
  const int bm = blockIdx.y * 64, bn = blockIdx.x * 64;
  const int tid = threadIdx.x;
  const int tx = tid & 15, ty = tid >> 4;
  float acc[4][4] = {};
  for (int k0 = 0; k0 < NN; k0 += 16) {
#pragma unroll
    for (int r = 0; r < 4; ++r) {
      const int m = (tid >> 4) + r * 16, kk = tid & 15;
      As[kk][m] = S[(size_t)(bm + m) * NN + k0 + kk];
    }
#pragma unroll
    for (int r = 0; r < 4; ++r) {
      const int kk = (tid >> 6) + r * 4, c = tid & 63;
      Bs[kk][c] = S[(size_t)(k0 + kk) * NN + bn + c];
    }
    __syncthreads();
#pragma unroll
    for (int kk = 0; kk < 16; ++kk) {
      float a[4], b[4];
#pragma unroll
      for (int i = 0; i < 4; ++i) a[i] = As[kk][ty * 4 + i];
#pragma unroll
      for (int j = 0; j < 4; ++j) b[j] = Bs[kk][tx * 4 + j];
#pragma unroll
      for (int i = 0; i < 4; ++i)
#pragma unroll
        for (int j = 0; j < 4; ++j) acc[i][j] += a[i] * b[j];
    }
    __syncthreads();
  }
#pragma unroll
  for (int i = 0; i < 4; ++i) {
    const int row = bm + ty * 4 + i;
#pragma unroll
    for (int j = 0; j < 4; ++j) {
      const int col = bn + tx * 4 + j;
      const float val = 2.f * acc[i][j] - (row == col ? 1.f : 0.f);
      unsigned short hi, lo;
      split_bf16(val, hi, lo);
      S2h[(size_t)row * NN + col] = hi;
      S2l[(size_t)row * NN + col] = lo;
    }
  }
}

// ---------------------------------------------------------------------------
// XT[j][node] (bf16 hi/lo) = transpose+split of xg slice0 (fp32 strided).
template <int C>
__global__ void xt_convert_kernel(const float* __restrict__ xg,
                                  unsigned short* __restrict__ XTh,
                                  unsigned short* __restrict__ XTl) {
  constexpr int LDR = B_ * 3 * C;
  __shared__ float tile[64][65];
  const int bj = blockIdx.x * 64, bn = blockIdx.y * 64;
  const int tid = threadIdx.x;
  {
    const int jl = tid & 63, nq = tid >> 6;
    const int j = bj + jl;
    const int b = j / C, c = j - b * C;
    const size_t base = (size_t)b * (3 * C) + c;
#pragma unroll
    for (int r = 0; r < 16; ++r) {
      const int node = bn + nq + r * 4;
      tile[nq + r * 4][jl] = xg[(size_t)node * LDR + base];
    }
  }
  __syncthreads();
  const int nl = tid & 63, jq = tid >> 6;
#pragma unroll
  for (int r = 0; r < 16; ++r) {
    const int j = bj + jq + r * 4;
    const float v = tile[nl][jq + r * 4];
    unsigned short hi, lo;
    split_bf16(v, hi, lo);
    XTh[(size_t)j * NN + bn + nl] = hi;
    XTl[(size_t)j * NN + bn + nl] = lo;
  }
}

// ---------------------------------------------------------------------------
// Graph conv, m97-style: per block 64 nodes x 128 j, both supports.
// LDS: A = {S1h,S1l,S2h,S2l}[64][32], B = {Xh,Xl}[128][32] (32 KB, linear).
// Wave w: slice = w>>1, j-half = (w&1)*64; 4x4 16x16 frags, 3 MFMA per pair.
template <int C>
__global__ void graph_mfma_kernel(const unsigned short* __restrict__ S1h,
                                  const unsigned short* __restrict__ S1l,
                                  const unsigned short* __restrict__ S2h,
                                  const unsigned short* __restrict__ S2l,
                                  const unsigned short* __restrict__ XTh,
                                  const unsigned short* __restrict__ XTl,
                                  float* __restrict__ xg) {
  constexpr int LDR = B_ * 3 * C;
  constexpr int W = B_ * C;
  __shared__ __align__(16) unsigned short sA[4 * 64 * 32];   // 16 KB
  __shared__ __align__(16) unsigned short sB[2 * 128 * 32];  // 16 KB
  const int bj = blockIdx.x * 128;
  const int bn = blockIdx.y * 64;
  const int tid = threadIdx.x;
  const int w = tid >> 6, lane = tid & 63;
  const int row = lane & 15, kq = lane >> 4;

  // staging roles (per wave): A-array w; B: waves 0,1 -> Xh halves, 2,3 -> Xl.
  const unsigned short* myA = (w == 0) ? S1h : (w == 1) ? S1l : (w == 2) ? S2h : S2l;
  const unsigned short* myB = (w < 2) ? XTh : XTl;
  const int bhalf = (w & 1) * 64;
  unsigned short* ldsA_w = sA + w * (64 * 32);
  unsigned short* ldsB_w = sB + (w < 2 ? 0 : 128 * 32) + bhalf * 32;
  const int srow = lane >> 2;   // 0..15 within 16-row stage chunk
  const int scol = lane & 3;    // 16B chunk

  // compute roles
  const int s = w >> 1;
  const int jhalf = (w & 1) * 64;
  const unsigned short* Ah_lds = sA + (2 * s) * (64 * 32);
  const unsigned short* Al_lds = sA + (2 * s + 1) * (64 * 32);
  const unsigned short* Bh_lds = sB;
  const unsigned short* Bl_lds = sB + 128 * 32;

  f32x4 acc[4][4] = {};
  for (int k0 = 0; k0 < NN; k0 += 32) {
#pragma unroll
    for (int i = 0; i < 4; ++i) {
      const unsigned short* g = myA + (size_t)(bn + i * 16 + srow) * NN + k0 + scol * 8;
      gload_lds16(g, ldsA_w + i * 16 * 32);
    }
#pragma unroll
    for (int i = 0; i < 4; ++i) {
      const unsigned short* g = myB + (size_t)(bj + bhalf + i * 16 + srow) * NN + k0 + scol * 8;
      gload_lds16(g, ldsB_w + i * 16 * 32);
    }
    __syncthreads();
    short8 ah[4], al[4];
#pragma unroll
    for (int mt = 0; mt < 4; ++mt) {
      ah[mt] = *(const short8*)(Ah_lds + (mt * 16 + row) * 32 + kq * 8);
      al[mt] = *(const short8*)(Al_lds + (mt * 16 + row) * 32 + kq * 8);
    }
#pragma unroll
    for (int nt = 0; nt < 4; ++nt) {
      const short8 bh = *(const short8*)(Bh_lds + (jhalf + nt * 16 + row) * 32 + kq * 8);
      const short8 bl = *(const short8*)(Bl_lds + (jhalf + nt * 16 + row) * 32 + kq * 8);
#pragma unroll
      for (int mt = 0; mt < 4; ++mt) {
        acc[mt][nt] = __builtin_amdgcn_mfma_f32_16x16x32_bf16(ah[mt], bh, acc[mt][nt], 0, 0, 0);
        acc[mt][nt] = __builtin_amdgcn_mfma_f32_16x16x32_bf16(ah[mt], bl, acc[mt][nt], 0, 0, 0);
        acc[mt][nt] = __builtin_amdgcn_mfma_f32_16x16x32_bf16(al[mt], bh, acc[mt][nt], 0, 0, 0);
      }
    }
    __syncthreads();
  }
  // D mapping (hw-verified r3/r4): col = lane&15 -> j, row = (lane>>4)*4+reg -> node.
  const int slice_off = (s + 1) * C;
#pragma unroll
  for (int nt = 0; nt < 4; ++nt) {
    const int j = bj + jhalf + nt * 16 + row;
    if (j < W) {
      const int b = j / C, c = j - b * C;
      const size_t base = (size_t)b * (3 * C) + c + slice_off;
#pragma unroll
      for (int mt = 0; mt < 4; ++mt) {
        const int node0 = bn + mt * 16 + kq * 4;
#pragma unroll
        for (int r = 0; r < 4; ++r)
          xg[(size_t)(node0 + r) * LDR + base] = acc[mt][nt][r];
      }
    }
  }
}

// ---------------------------------------------------------------------------
// out = act( A (65536 x KK) @ W (KK x NO) + bias ); ACT: 0=none,1=sigmoid,2=tanh
template <int KK, int NO, int ACT>
__global__ void dense_kernel(const float* __restrict__ A, const float* __restrict__ W,
                             const float* __restrict__ bias, float* __restrict__ out) {
  constexpr int NO16 = NO / 16;
  __shared__ float As[16][68];
  __shared__ float Ws[16][NO + 4];
  const int row0 = blockIdx.x * 64;
  const int tid = threadIdx.x;
  const int tx = tid & 15, ty = tid >> 4;
  float acc[4][NO16] = {};
  for (int k0 = 0; k0 < KK; k0 += 16) {
#pragma unroll
    for (int r = 0; r < 4; ++r) {
      const int m = (tid >> 4) + r * 16, kk = tid & 15;
      const int k = k0 + kk;
      As[kk][m] = (k < KK) ? A[(size_t)(row0 + m) * KK + k] : 0.f;
    }
    for (int i = tid; i < 16 * NO; i += 256) {
      const int kk = i / NO, c = i - kk * NO;
      const int k = k0 + kk;
      Ws[kk][c] = (k < KK) ? W[(size_t)k * NO + c] : 0.f;
    }
    __syncthreads();
#pragma unroll
    for (int kk = 0; kk < 16; ++kk) {
      float a[4];
#pragma unroll
      for (int i = 0; i < 4; ++i) a[i] = As[kk][ty * 4 + i];
#pragma unroll
      for (int j = 0; j < NO16; ++j) {
        const float wv = Ws[kk][tx * NO16 + j];
#pragma unroll
        for (int i = 0; i < 4; ++i) acc[i][j] += a[i] * wv;
      }
    }
    __syncthreads();
  }
#pragma unroll
  for (int j = 0; j < NO16; ++j) {
    const int c = tx * NO16 + j;
    const float bv = bias[c];
#pragma unroll
    for (int i = 0; i < 4; ++i) {
      float v = acc[i][j] + bv;
      if (ACT == 1) v = 1.f / (1.f + expf(-v));
      else if (ACT == 2) v = tanhf(v);
      out[(size_t)(row0 + ty * 4 + i) * NO + c] = v;
    }
  }
}

// ---------------------------------------------------------------------------
// Elementwise builders. One thread per (n,b); idx = n*B + b.
__global__ void build_enc_kernel(const float* __restrict__ x, const float* __restrict__ h,
                                 float* __restrict__ xg, int t) {
  const int idx = blockIdx.x * 256 + threadIdx.x;
  const int n = idx >> 6, b = idx & 63;
  float* dst = xg + (size_t)idx * 195;
  dst[0] = x[((size_t)b * T_ + t) * NN + n];
  const float* hp = h + (size_t)idx * 64;
#pragma unroll
  for (int i = 0; i < 64; ++i) dst[1 + i] = hp[i];
}

__global__ void cand_enc_kernel(const float* __restrict__ zr, const float* __restrict__ h,
                                float* __restrict__ xg) {
  const int idx = blockIdx.x * 256 + threadIdx.x;
  float* dst = xg + (size_t)idx * 195 + 1;
  const float* z = zr + (size_t)idx * 128;
  const float* hp = h + (size_t)idx * 64;
#pragma unroll
  for (int i = 0; i < 64; ++i) dst[i] = z[i] * hp[i];
}

template <int H>
__global__ void combine_kernel(const float* __restrict__ zr, const float* __restrict__ hcb,
                               float* __restrict__ h) {
  const int e = blockIdx.x * 256 + threadIdx.x;
  const int idx = e / H, i = e - idx * H;
  const float r = zr[(size_t)idx * (2 * H) + H + i];
  h[e] = r * h[e] + (1.f - r) * hcb[e];
}

__global__ void attn_kernel(const float* __restrict__ h, const float* __restrict__ Wq,
                            const float* __restrict__ Mem, const float* __restrict__ FCE,
                            float* __restrict__ proto, float* __restrict__ WE) {
  __shared__ float sWq[64 * 32];
  __shared__ float sM[10 * 32];
  __shared__ float sF[32 * 8];
  const int tid = threadIdx.x;
  for (int i = tid; i < 64 * 32; i += 256) sWq[i] = Wq[i];
  for (int i = tid; i < 10 * 32; i += 256) sM[i] = Mem[i];
  for (int i = tid; i < 32 * 8; i += 256) sF[i] = FCE[i];
  __syncthreads();
  const int idx = blockIdx.x * 256 + tid;
  const float* hp = h + (size_t)idx * 64;
  float q[32] = {};
  for (int i0 = 0; i0 < 16; ++i0) {
    const float4 h4 = *(const float4*)(hp + i0 * 4);
#pragma unroll
    for (int jj = 0; jj < 4; ++jj) {
      const float hv = ((const float*)&h4)[jj];
      const int i = i0 * 4 + jj;
#pragma unroll
      for (int c = 0; c < 32; ++c) q[c] += hv * sWq[i * 32 + c];
    }
  }
  float lg[10];
  float mx = -1e30f;
#pragma unroll
  for (int m = 0; m < 10; ++m) {
    float s = 0.f;
#pragma unroll
    for (int c = 0; c < 32; ++c) s += q[c] * sM[m * 32 + c];
    lg[m] = s;
    mx = fmaxf(mx, s);
  }
  float den = 0.f;
#pragma unroll
  for (int m = 0; m < 10; ++m) { lg[m] = expf(lg[m] - mx); den += lg[m]; }
  const float inv = 1.f / den;
  float p[32] = {};
#pragma unroll
  for (int m = 0; m < 10; ++m) {
    const float a = lg[m] * inv;
#pragma unroll
    for (int c = 0; c < 32; ++c) p[c] += a * sM[m * 32 + c];
  }
  float* pd = proto + (size_t)idx * 32;
#pragma unroll
  for (int c = 0; c < 32; ++c) pd[c] = p[c];
  float* wd = WE + (size_t)idx * 8;
#pragma unroll
  for (int e = 0; e < 8; ++e) {
    float s = 0.f;
#pragma unroll
    for (int c = 0; c < 32; ++c) s += p[c] * sF[c * 8 + e];
    wd[e] = s;
  }
}

__global__ void build_h0_kernel(const float* __restrict__ hA, const float* __restrict__ proto,
                                float* __restrict__ hB) {
  const int idx = blockIdx.x * 256 + threadIdx.x;
  float* dst = hB + (size_t)idx * 96;
  const float* s1 = hA + (size_t)idx * 64;
  const float* s2 = proto + (size_t)idx * 32;
#pragma unroll
  for (int i = 0; i < 64; ++i) dst[i] = s1[i];
#pragma unroll
  for (int i = 0; i < 32; ++i) dst[64 + i] = s2[i];
}

__global__ void build_dec_kernel(const float* __restrict__ go, const float* __restrict__ ycov,
                                 const float* __restrict__ hB, float* __restrict__ xg, int t) {
  const int idx = blockIdx.x * 256 + threadIdx.x;
  const int n = idx >> 6, b = idx & 63;
  float* dst = xg + (size_t)idx * 294;
  dst[0] = go[idx];
  dst[1] = ycov[((size_t)b * HOR_ + t) * NN + n];
  const float* hp = hB + (size_t)idx * 96;
#pragma unroll
  for (int i = 0; i < 96; ++i) dst[2 + i] = hp[i];
}

__global__ void cand_dec_kernel(const float* __restrict__ zr, const float* __restrict__ h,
                                float* __restrict__ xg) {
  const int idx = blockIdx.x * 256 + threadIdx.x;
  float* dst = xg + (size_t)idx * 294 + 2;
  const float* z = zr + (size_t)idx * 192;
  const float* hp = h + (size_t)idx * 96;
#pragma unroll
  for (int i = 0; i < 96; ++i) dst[i] = z[i] * hp[i];
}

__global__ void proj_kernel(const float* __restrict__ h, const float* __restrict__ pW,
                            const float* __restrict__ pb, float* __restrict__ go,
                            float* __restrict__ out, int t) {
  __shared__ float sW[96];
  if (threadIdx.x < 96) sW[threadIdx.x] = pW[threadIdx.x];
  __syncthreads();
  const int idx = blockIdx.x * 256 + threadIdx.x;
  const float* hp = h + (size_t)idx * 96;
  float acc = pb[0];
  for (int j0 = 0; j0 < 24; ++j0) {
    const float4 h4 = *(const float4*)(hp + j0 * 4);
    acc += h4.x * sW[j0 * 4] + h4.y * sW[j0 * 4 + 1] + h4.z * sW[j0 * 4 + 2] + h4.w * sW[j0 * 4 + 3];
  }
  go[idx] = acc;
  const int n = idx >> 6, b = idx & 63;
  out[((size_t)b * HOR_ + t) * NN + n] = acc;
}

// ---------------------------------------------------------------------------
extern "C" void kernel_launch(void* const* d_in, const int* in_sizes, int n_in,
                              void* d_out, int out_size, void* d_ws, size_t ws_size,
                              hipStream_t stream) {
  const float* x    = (const float*)d_in[0];
  const float* ycov = (const float*)d_in[1];
  const float* emb  = (const float*)d_in[2];
  const float* egW  = (const float*)d_in[3];
  const float* egb  = (const float*)d_in[4];
  const float* euW  = (const float*)d_in[5];
  const float* eub  = (const float*)d_in[6];
  const float* Mem  = (const float*)d_in[7];
  const float* Wq   = (const float*)d_in[8];
  const float* FCE  = (const float*)d_in[9];
  const float* dgW  = (const float*)d_in[10];
  const float* dgb  = (const float*)d_in[11];
  const float* duW  = (const float*)d_in[12];
  const float* dub  = (const float*)d_in[13];
  const float* pW   = (const float*)d_in[14];
  const float* pb   = (const float*)d_in[15];
  float* out = (float*)d_out;

  char* w = (char*)d_ws;
  auto alloc = [&](size_t bytes) {
    void* p = (void*)w;
    w += (bytes + 255) & ~(size_t)255;
    return p;
  };
  float* S1    = (float*)alloc((size_t)NN * NN * 4);
  float* xg    = (float*)alloc((size_t)NN * B_ * 294 * 4);
  float* zr    = (float*)alloc((size_t)NN * B_ * 192 * 4);
  float* hc    = (float*)alloc((size_t)NN * B_ * 96 * 4);
  float* hA    = (float*)alloc((size_t)NN * B_ * 64 * 4);
  float* hB    = (float*)alloc((size_t)NN * B_ * 96 * 4);
  float* go    = (float*)alloc((size_t)NN * B_ * 4);
  float* proto = (float*)alloc((size_t)NN * B_ * 32 * 4);
  float* WE    = (float*)alloc((size_t)NN * B_ * 8 * 4);
  unsigned short* S1h = (unsigned short*)alloc((size_t)NN * NN * 2);
  unsigned short* S1l = (unsigned short*)alloc((size_t)NN * NN * 2);
  unsigned short* S2h = (unsigned short*)alloc((size_t)NN * NN * 2);
  unsigned short* S2l = (unsigned short*)alloc((size_t)NN * NN * 2);
  unsigned short* XTh = (unsigned short*)alloc((size_t)B_ * 98 * NN * 2);
  unsigned short* XTl = (unsigned short*)alloc((size_t)B_ * 98 * NN * 2);
  (void)ws_size; (void)in_sizes; (void)n_in; (void)out_size;

  const dim3 blk(256);

  // ---- encoder supports ----
  gemm_nt_kernel<<<dim3(16, 16), blk, 0, stream>>>(emb, emb, S1, NN, 8);
  relu_softmax_kernel<<<NN, blk, 0, stream>>>(S1, S1h, S1l);
  cheb_kernel<<<dim3(16, 16), blk, 0, stream>>>(S1, S2h, S2l);

  hipMemsetAsync(hA, 0, (size_t)NN * B_ * 64 * sizeof(float), stream);

  // ---- encoder scan ----  (W_enc = 4160, padded grid 33*128 = 4224)
  for (int t = 0; t < T_; ++t) {
    build_enc_kernel<<<256, blk, 0, stream>>>(x, hA, xg, t);
    xt_convert_kernel<65><<<dim3(65, 16), blk, 0, stream>>>(xg, XTh, XTl);
    graph_mfma_kernel<65><<<dim3(33, 16), blk, 0, stream>>>(S1h, S1l, S2h, S2l, XTh, XTl, xg);
    dense_kernel<195, 128, 1><<<1024, blk, 0, stream>>>(xg, egW, egb, zr);
    cand_enc_kernel<<<256, blk, 0, stream>>>(zr, hA, xg);
    xt_convert_kernel<65><<<dim3(65, 16), blk, 0, stream>>>(xg, XTh, XTl);
    graph_mfma_kernel<65><<<dim3(33, 16), blk, 0, stream>>>(S1h, S1l, S2h, S2l, XTh, XTl, xg);
    dense_kernel<195, 64, 2><<<1024, blk, 0, stream>>>(xg, euW, eub, hc);
    combine_kernel<64><<<16384, blk, 0, stream>>>(zr, hc, hA);
  }

  // ---- attention / memory / decoder supports ----
  attn_kernel<<<256, blk, 0, stream>>>(hA, Wq, Mem, FCE, proto, WE);
  gemm_nt_kernel<<<dim3(16, 16), blk, 0, stream>>>(WE, WE, S1, NN, 512);
  relu_softmax_kernel<<<NN, blk, 0, stream>>>(S1, S1h, S1l);
  cheb_kernel<<<dim3(16, 16), blk, 0, stream>>>(S1, S2h, S2l);
  build_h0_kernel<<<256, blk, 0, stream>>>(hA, proto, hB);
  hipMemsetAsync(go, 0, (size_t)NN * B_ * sizeof(float), stream);

  // ---- decoder scan ----  (W_dec = 6272 = 49*128 exactly)
  for (int t = 0; t < HOR_; ++t) {
    build_dec_kernel<<<256, blk, 0, stream>>>(go, ycov, hB, xg, t);
    xt_convert_kernel<98><<<dim3(98, 16), blk, 0, stream>>>(xg, XTh, XTl);
    graph_mfma_kernel<98><<<dim3(49, 16), blk, 0, stream>>>(S1h, S1l, S2h, S2l, XTh, XTl, xg);
    dense_kernel<294, 192, 1><<<1024, blk, 0, stream>>>(xg, dgW, dgb, zr);
    cand_dec_kernel<<<256, blk, 0, stream>>>(zr, hB, xg);
    xt_convert_kernel<98><<<dim3(98, 16), blk, 0, stream>>>(xg, XTh, XTl);
    graph_mfma_kernel<98><<<dim3(49, 16), blk, 0, stream>>>(S1h, S1l, S2h, S2l, XTh, XTl, xg);
    dense_kernel<294, 96, 2><<<1024, blk, 0, stream>>>(xg, duW, dub, hc);
    combine_kernel<96><<<24576, blk, 0, stream>>>(zr, hc, hB);
    proj_kernel<<<256, blk, 0, stream>>>(hB, pW, pb, go, out, t);
  }
}

// Round 6
// 7481.911 us; speedup vs baseline: 2.7846x; 1.4002x over previous
//
#include <hip/hip_runtime.h>
#include <hip/hip_bf16.h>

// MMGCRN: graph convs + dense layers on MFMA (bf16x3 split = fp32-class).
// B=64, T=12, N=1024, HOR=12, RNN=64, DEC=96, K=3.
constexpr int B_ = 64, T_ = 12, NN = 1024, HOR_ = 12;

typedef __attribute__((ext_vector_type(8))) short short8;   // 8 bf16 (4 VGPRs)
typedef __attribute__((ext_vector_type(4))) float f32x4;    // MFMA C/D frag
typedef unsigned short ushort_t;

static __device__ inline ushort_t f2bh(float v) {
  __hip_bfloat16 h = __float2bfloat16(v);
  return *reinterpret_cast<ushort_t*>(&h);
}
static __device__ inline float bh2f(ushort_t u) {
  __hip_bfloat16 h = *reinterpret_cast<__hip_bfloat16*>(&u);
  return __bfloat162float(h);
}
static __device__ inline void split_bf16(float v, ushort_t& hi, ushort_t& lo) {
  hi = f2bh(v);
  lo = f2bh(v - bh2f(hi));
}

// async global->LDS, 16B per lane (LDS dest = wave-uniform base + lane*16).
static __device__ inline void gload_lds16(const ushort_t* g, ushort_t* l) {
  __builtin_amdgcn_global_load_lds(
      (const __attribute__((address_space(1))) unsigned int*)g,
      (__attribute__((address_space(3))) unsigned int*)l, 16, 0, 0);
}

// ---------------------------------------------------------------------------
// C = A (M x Kd) @ B (Ncol x Kd)^T, row-major, 64x64 tile, 4x4/thread. fp32.
__global__ void gemm_nt_kernel(const float* __restrict__ A, const float* __restrict__ Bm,
                               float* __restrict__ C, int Ncol, int Kd) {
  __shared__ float As[16][68];
  __shared__ float Bs[16][68];
  const int bm = blockIdx.y * 64, bn = blockIdx.x * 64;
  const int tid = threadIdx.x;
  const int tx = tid & 15, ty = tid >> 4;
  float acc[4][4] = {};
  for (int k0 = 0; k0 < Kd; k0 += 16) {
#pragma unroll
    for (int r = 0; r < 4; ++r) {
      const int m = (tid >> 4) + r * 16;
      const int kk = tid & 15;
      const int k = k0 + kk;
      As[kk][m] = (k < Kd) ? A[(size_t)(bm + m) * Kd + k] : 0.f;
      Bs[kk][m] = (k < Kd) ? Bm[(size_t)(bn + m) * Kd + k] : 0.f;
    }
    __syncthreads();
#pragma unroll
    for (int kk = 0; kk < 16; ++kk) {
      float a[4], b[4];
#pragma unroll
      for (int i = 0; i < 4; ++i) a[i] = As[kk][ty * 4 + i];
#pragma unroll
      for (int j = 0; j < 4; ++j) b[j] = Bs[kk][tx * 4 + j];
#pragma unroll
      for (int i = 0; i < 4; ++i)
#pragma unroll
        for (int j = 0; j < 4; ++j) acc[i][j] += a[i] * b[j];
    }
    __syncthreads();
  }
#pragma unroll
  for (int i = 0; i < 4; ++i)
#pragma unroll
    for (int j = 0; j < 4; ++j)
      C[(size_t)(bm + ty * 4 + i) * Ncol + bn + tx * 4 + j] = acc[i][j];
}

// ---------------------------------------------------------------------------
// In-place row softmax(relu(x)) over 1024 cols; also emits bf16 hi/lo split.
__global__ void relu_softmax_kernel(float* __restrict__ S, ushort_t* __restrict__ Sh,
                                    ushort_t* __restrict__ Sl) {
  const int row = blockIdx.x;
  float* r = S + (size_t)row * NN;
  const int tid = threadIdx.x;  // 256
  float v[4];
  float mx = 0.f;
#pragma unroll
  for (int j = 0; j < 4; ++j) {
    float xv = fmaxf(r[tid + j * 256], 0.f);
    v[j] = xv;
    mx = fmaxf(mx, xv);
  }
#pragma unroll
  for (int off = 1; off < 64; off <<= 1) mx = fmaxf(mx, __shfl_xor(mx, off));
  __shared__ float sred[4];
  const int wv = tid >> 6;
  if ((tid & 63) == 0) sred[wv] = mx;
  __syncthreads();
  mx = fmaxf(fmaxf(sred[0], sred[1]), fmaxf(sred[2], sred[3]));
  __syncthreads();
  float s = 0.f;
#pragma unroll
  for (int j = 0; j < 4; ++j) { v[j] = expf(v[j] - mx); s += v[j]; }
#pragma unroll
  for (int off = 1; off < 64; off <<= 1) s += __shfl_xor(s, off);
  if ((tid & 63) == 0) sred[wv] = s;
  __syncthreads();
  s = sred[0] + sred[1] + sred[2] + sred[3];
  const float inv = 1.f / s;
#pragma unroll
  for (int j = 0; j < 4; ++j) {
    const float sv = v[j] * inv;
    const size_t e = (size_t)row * NN + tid + j * 256;
    r[tid + j * 256] = sv;
    ushort_t hi, lo;
    split_bf16(sv, hi, lo);
    Sh[e] = hi;
    Sl[e] = lo;
  }
}

// ---------------------------------------------------------------------------
// S2 = 2*S@S - I, emitted directly as bf16 hi/lo split.
__global__ void cheb_kernel(const float* __restrict__ S, ushort_t* __restrict__ S2h,
                            ushort_t* __restrict__ S2l) {
  __shared__ float As[16][68];
  __shared__ float Bs[16][68];
  const int bm = blockIdx.y * 64, bn = blockIdx.x * 64;
  const int tid = threadIdx.x;
  const int tx = tid & 15, ty = tid >> 4;
  float acc[4][4] = {};
  for (int k0 = 0; k0 < NN; k0 += 16) {
#pragma unroll
    for (int r = 0; r < 4; ++r) {
      const int m = (tid >> 4) + r * 16, kk = tid & 15;
      As[kk][m] = S[(size_t)(bm + m) * NN + k0 + kk];
    }
#pragma unroll
    for (int r = 0; r < 4; ++r) {
      const int kk = (tid >> 6) + r * 4, c = tid & 63;
      Bs[kk][c] = S[(size_t)(k0 + kk) * NN + bn + c];
    }
    __syncthreads();
#pragma unroll
    for (int kk = 0; kk < 16; ++kk) {
      float a[4], b[4];
#pragma unroll
      for (int i = 0; i < 4; ++i) a[i] = As[kk][ty * 4 + i];
#pragma unroll
      for (int j = 0; j < 4; ++j) b[j] = Bs[kk][tx * 4 + j];
#pragma unroll
      for (int i = 0; i < 4; ++i)
#pragma unroll
        for (int j = 0; j < 4; ++j) acc[i][j] += a[i] * b[j];
    }
    __syncthreads();
  }
#pragma unroll
  for (int i = 0; i < 4; ++i) {
    const int row = bm + ty * 4 + i;
#pragma unroll
    for (int j = 0; j < 4; ++j) {
      const int col = bn + tx * 4 + j;
      const float val = 2.f * acc[i][j] - (row == col ? 1.f : 0.f);
      ushort_t hi, lo;
      split_bf16(val, hi, lo);
      S2h[(size_t)row * NN + col] = hi;
      S2l[(size_t)row * NN + col] = lo;
    }
  }
}

// ---------------------------------------------------------------------------
// Wt[no][k] = W[k][no], bf16 hi/lo, zero-padded to [NOP][KP].
__global__ void wt_kernel(const float* __restrict__ W, ushort_t* __restrict__ Wth,
                          ushort_t* __restrict__ Wtl, int KK, int NO, int KP, int NOP) {
  const int e = blockIdx.x * 256 + threadIdx.x;
  if (e >= NOP * KP) return;
  const int no = e / KP, k = e - no * KP;
  const float v = (no < NO && k < KK) ? W[(size_t)k * NO + no] : 0.f;
  ushort_t hi, lo;
  split_bf16(v, hi, lo);
  Wth[e] = hi;
  Wtl[e] = lo;
}

// ---------------------------------------------------------------------------
// prep: build cell input on the fly; write Ag (idx-major, bf16 hi/lo) and
// XT (j-major transpose, bf16 hi/lo). One block = 64 j x 64 nodes.
// MODE 0: enc build [x_t, h]; 1: enc cand [x_t, z*h];
//      2: dec build [go, yc, h]; 3: dec cand [go, yc, z*h].
template <int C, int KP, int MODE>
__global__ void prep_kernel(const float* __restrict__ src0, const float* __restrict__ src1,
                            const float* __restrict__ hst, const float* __restrict__ zr,
                            ushort_t* __restrict__ Agh, ushort_t* __restrict__ Agl,
                            ushort_t* __restrict__ XTh, ushort_t* __restrict__ XTl, int t) {
  __shared__ float tile[64][65];
  const int bj = blockIdx.x * 64, bn = blockIdx.y * 64;
  const int tid = threadIdx.x;
  const int jl = tid & 63, nq = tid >> 6;
  const int j = bj + jl;
  const int b = j / C, c = j - b * C;
#pragma unroll
  for (int r = 0; r < 16; ++r) {
    const int node = bn + nq + r * 4;
    const int idx = node * 64 + b;
    float v;
    if (MODE == 0) {
      v = (c == 0) ? src0[((size_t)b * T_ + t) * NN + node]
                   : hst[(size_t)idx * 64 + (c - 1)];
    } else if (MODE == 1) {
      v = (c == 0) ? src0[((size_t)b * T_ + t) * NN + node]
                   : zr[(size_t)idx * 128 + (c - 1)] * hst[(size_t)idx * 64 + (c - 1)];
    } else if (MODE == 2) {
      v = (c == 0) ? src0[idx]
        : (c == 1) ? src1[((size_t)b * HOR_ + t) * NN + node]
                   : hst[(size_t)idx * 96 + (c - 2)];
    } else {
      v = (c == 0) ? src0[idx]
        : (c == 1) ? src1[((size_t)b * HOR_ + t) * NN + node]
                   : zr[(size_t)idx * 192 + (c - 2)] * hst[(size_t)idx * 96 + (c - 2)];
    }
    tile[nq + r * 4][jl] = v;
    ushort_t hi, lo;
    split_bf16(v, hi, lo);
    Agh[(size_t)idx * KP + c] = hi;
    Agl[(size_t)idx * KP + c] = lo;
  }
  __syncthreads();
  const int nl = tid & 63, jq = tid >> 6;
#pragma unroll
  for (int r = 0; r < 16; ++r) {
    const int jj = bj + jq + r * 4;
    const float v = tile[nl][jq + r * 4];
    ushort_t hi, lo;
    split_bf16(v, hi, lo);
    XTh[(size_t)jj * NN + bn + nl] = hi;
    XTl[(size_t)jj * NN + bn + nl] = lo;
  }
}

// ---------------------------------------------------------------------------
// Graph conv, LDS-staged: per block 64 nodes x 128 j, both supports.
// Writes slices 1,2 of Ag (bf16 hi/lo split).
template <int C, int KP>
__global__ void graph_mfma_kernel(const ushort_t* __restrict__ S1h,
                                  const ushort_t* __restrict__ S1l,
                                  const ushort_t* __restrict__ S2h,
                                  const ushort_t* __restrict__ S2l,
                                  const ushort_t* __restrict__ XTh,
                                  const ushort_t* __restrict__ XTl,
                                  ushort_t* __restrict__ Agh, ushort_t* __restrict__ Agl) {
  constexpr int W = B_ * C;
  __shared__ __align__(16) ushort_t sA[4 * 64 * 32];   // 16 KB
  __shared__ __align__(16) ushort_t sB[2 * 128 * 32];  // 16 KB
  const int bj = blockIdx.x * 128;
  const int bn = blockIdx.y * 64;
  const int tid = threadIdx.x;
  const int w = tid >> 6, lane = tid & 63;
  const int row = lane & 15, kq = lane >> 4;

  const ushort_t* myA = (w == 0) ? S1h : (w == 1) ? S1l : (w == 2) ? S2h : S2l;
  const ushort_t* myB = (w < 2) ? XTh : XTl;
  const int bhalf = (w & 1) * 64;
  ushort_t* ldsA_w = sA + w * (64 * 32);
  ushort_t* ldsB_w = sB + (w < 2 ? 0 : 128 * 32) + bhalf * 32;
  const int srow = lane >> 2;
  const int scol = lane & 3;

  const int s = w >> 1;
  const int jhalf = (w & 1) * 64;
  const ushort_t* Ah_lds = sA + (2 * s) * (64 * 32);
  const ushort_t* Al_lds = sA + (2 * s + 1) * (64 * 32);
  const ushort_t* Bh_lds = sB;
  const ushort_t* Bl_lds = sB + 128 * 32;

  f32x4 acc[4][4] = {};
  for (int k0 = 0; k0 < NN; k0 += 32) {
#pragma unroll
    for (int i = 0; i < 4; ++i) {
      const ushort_t* g = myA + (size_t)(bn + i * 16 + srow) * NN + k0 + scol * 8;
      gload_lds16(g, ldsA_w + i * 16 * 32);
    }
#pragma unroll
    for (int i = 0; i < 4; ++i) {
      const ushort_t* g = myB + (size_t)(bj + bhalf + i * 16 + srow) * NN + k0 + scol * 8;
      gload_lds16(g, ldsB_w + i * 16 * 32);
    }
    __syncthreads();
    short8 ah[4], al[4];
#pragma unroll
    for (int mt = 0; mt < 4; ++mt) {
      ah[mt] = *(const short8*)(Ah_lds + (mt * 16 + row) * 32 + kq * 8);
      al[mt] = *(const short8*)(Al_lds + (mt * 16 + row) * 32 + kq * 8);
    }
#pragma unroll
    for (int nt = 0; nt < 4; ++nt) {
      const short8 bh = *(const short8*)(Bh_lds + (jhalf + nt * 16 + row) * 32 + kq * 8);
      const short8 bl = *(const short8*)(Bl_lds + (jhalf + nt * 16 + row) * 32 + kq * 8);
#pragma unroll
      for (int mt = 0; mt < 4; ++mt) {
        acc[mt][nt] = __builtin_amdgcn_mfma_f32_16x16x32_bf16(ah[mt], bh, acc[mt][nt], 0, 0, 0);
        acc[mt][nt] = __builtin_amdgcn_mfma_f32_16x16x32_bf16(ah[mt], bl, acc[mt][nt], 0, 0, 0);
        acc[mt][nt] = __builtin_amdgcn_mfma_f32_16x16x32_bf16(al[mt], bh, acc[mt][nt], 0, 0, 0);
      }
    }
    __syncthreads();
  }
  // D mapping: col (=j) = lane&15, row (=node) = (lane>>4)*4 + reg.
  const int slice_off = (s + 1) * C;
#pragma unroll
  for (int nt = 0; nt < 4; ++nt) {
    const int j = bj + jhalf + nt * 16 + row;
    if (j < W) {
      const int b = j / C, c = j - b * C;
      const size_t coloff = (size_t)(slice_off + c);
#pragma unroll
      for (int mt = 0; mt < 4; ++mt) {
        const int node0 = bn + mt * 16 + kq * 4;
#pragma unroll
        for (int r = 0; r < 4; ++r) {
          const size_t a = (size_t)((node0 + r) * 64 + b) * KP + coloff;
          ushort_t hi, lo;
          split_bf16(acc[mt][nt][r], hi, lo);
          Agh[a] = hi;
          Agl[a] = lo;
        }
      }
    }
  }
}

// ---------------------------------------------------------------------------
// Dense on MFMA: out = act(Ag(65536 x KP) @ Wt^T + bias), bf16x3 split.
// Block: 128 rows x NO cols; 4 waves, wave w = rows [w*32, +32).
// MODE 0: sigmoid -> outp(zr, stride NO=2H). MODE 1: fused GRU combine:
//   outp(h, stride H) = r*h + (1-r)*tanh(acc+bias), r from zrin.
template <int KP, int NO, int NOP, int MODE, int H>
__global__ void dense_mfma_kernel(const ushort_t* __restrict__ Agh,
                                  const ushort_t* __restrict__ Agl,
                                  const ushort_t* __restrict__ Wth,
                                  const ushort_t* __restrict__ Wtl,
                                  const float* __restrict__ bias,
                                  float* __restrict__ outp,
                                  const float* __restrict__ zrin) {
  constexpr int NFR = NO / 16;
  __shared__ __align__(16) ushort_t sAh[128 * 32];
  __shared__ __align__(16) ushort_t sAl[128 * 32];
  __shared__ __align__(16) ushort_t sBh[NOP * 32];
  __shared__ __align__(16) ushort_t sBl[NOP * 32];
  const int row0 = blockIdx.x * 128;
  const int tid = threadIdx.x;
  const int w = tid >> 6, lane = tid & 63;
  const int col16 = lane & 15, four = lane >> 4;
  const int srow = lane >> 2, scol = (lane & 3) * 8;
  f32x4 acc[2][NFR] = {};
  for (int k0 = 0; k0 < KP; k0 += 32) {
    for (int c = w; c < 8; c += 4) {
      const size_t g = (size_t)(row0 + c * 16 + srow) * KP + k0 + scol;
      gload_lds16(Agh + g, sAh + c * 512);
      gload_lds16(Agl + g, sAl + c * 512);
    }
    for (int c = w; c < NOP / 16; c += 4) {
      const size_t g = (size_t)(c * 16 + srow) * KP + k0 + scol;
      gload_lds16(Wth + g, sBh + c * 512);
      gload_lds16(Wtl + g, sBl + c * 512);
    }
    __syncthreads();
    short8 ah[2], al[2];
#pragma unroll
    for (int mt = 0; mt < 2; ++mt) {
      const int r = (w * 32 + mt * 16 + col16) * 32 + four * 8;
      ah[mt] = *(const short8*)(sAh + r);
      al[mt] = *(const short8*)(sAl + r);
    }
#pragma unroll
    for (int nt = 0; nt < NFR; ++nt) {
      const int r = (nt * 16 + col16) * 32 + four * 8;
      const short8 bh = *(const short8*)(sBh + r);
      const short8 bl = *(const short8*)(sBl + r);
#pragma unroll
      for (int mt = 0; mt < 2; ++mt) {
        acc[mt][nt] = __builtin_amdgcn_mfma_f32_16x16x32_bf16(ah[mt], bh, acc[mt][nt], 0, 0, 0);
        acc[mt][nt] = __builtin_amdgcn_mfma_f32_16x16x32_bf16(ah[mt], bl, acc[mt][nt], 0, 0, 0);
        acc[mt][nt] = __builtin_amdgcn_mfma_f32_16x16x32_bf16(al[mt], bh, acc[mt][nt], 0, 0, 0);
      }
    }
    __syncthreads();
  }
#pragma unroll
  for (int nt = 0; nt < NFR; ++nt) {
    const int col = nt * 16 + col16;
    const float bv = bias[col];
#pragma unroll
    for (int mt = 0; mt < 2; ++mt) {
      const int rbase = row0 + w * 32 + mt * 16 + four * 4;
#pragma unroll
      for (int r = 0; r < 4; ++r) {
        const int row = rbase + r;
        const float v = acc[mt][nt][r] + bv;
        if (MODE == 0) {
          outp[(size_t)row * NO + col] = 1.f / (1.f + expf(-v));
        } else {
          const float rg = zrin[(size_t)row * (2 * H) + H + col];
          const float hv = outp[(size_t)row * H + col];
          outp[(size_t)row * H + col] = rg * hv + (1.f - rg) * tanhf(v);
        }
      }
    }
  }
}

// ---------------------------------------------------------------------------
// attention + prototype + W_E + h0 build, fused. One thread per (n,b).
__global__ void attn_kernel(const float* __restrict__ h, const float* __restrict__ Wq,
                            const float* __restrict__ Mem, const float* __restrict__ FCE,
                            float* __restrict__ hB, float* __restrict__ WE) {
  __shared__ float sWq[64 * 32];
  __shared__ float sM[10 * 32];
  __shared__ float sF[32 * 8];
  const int tid = threadIdx.x;
  for (int i = tid; i < 64 * 32; i += 256) sWq[i] = Wq[i];
  for (int i = tid; i < 10 * 32; i += 256) sM[i] = Mem[i];
  for (int i = tid; i < 32 * 8; i += 256) sF[i] = FCE[i];
  __syncthreads();
  const int idx = blockIdx.x * 256 + tid;
  const float* hp = h + (size_t)idx * 64;
  float* hd = hB + (size_t)idx * 96;
  float q[32] = {};
  for (int i0 = 0; i0 < 16; ++i0) {
    const float4 h4 = *(const float4*)(hp + i0 * 4);
#pragma unroll
    for (int jj = 0; jj < 4; ++jj) {
      const float hv = ((const float*)&h4)[jj];
      hd[i0 * 4 + jj] = hv;  // h0 = [h, proto]
      const int i = i0 * 4 + jj;
#pragma unroll
      for (int c = 0; c < 32; ++c) q[c] += hv * sWq[i * 32 + c];
    }
  }
  float lg[10];
  float mx = -1e30f;
#pragma unroll
  for (int m = 0; m < 10; ++m) {
    float s = 0.f;
#pragma unroll
    for (int c = 0; c < 32; ++c) s += q[c] * sM[m * 32 + c];
    lg[m] = s;
    mx = fmaxf(mx, s);
  }
  float den = 0.f;
#pragma unroll
  for (int m = 0; m < 10; ++m) { lg[m] = expf(lg[m] - mx); den += lg[m]; }
  const float inv = 1.f / den;
  float p[32] = {};
#pragma unroll
  for (int m = 0; m < 10; ++m) {
    const float a = lg[m] * inv;
#pragma unroll
    for (int c = 0; c < 32; ++c) p[c] += a * sM[m * 32 + c];
  }
#pragma unroll
  for (int c = 0; c < 32; ++c) hd[64 + c] = p[c];
  float* wd = WE + (size_t)idx * 8;
#pragma unroll
  for (int e = 0; e < 8; ++e) {
    float s = 0.f;
#pragma unroll
    for (int c = 0; c < 32; ++c) s += p[c] * sF[c * 8 + e];
    wd[e] = s;
  }
}

__global__ void proj_kernel(const float* __restrict__ h, const float* __restrict__ pW,
                            const float* __restrict__ pb, float* __restrict__ go,
                            float* __restrict__ out, int t) {
  __shared__ float sW[96];
  if (threadIdx.x < 96) sW[threadIdx.x] = pW[threadIdx.x];
  __syncthreads();
  const int idx = blockIdx.x * 256 + threadIdx.x;
  const float* hp = h + (size_t)idx * 96;
  float acc = pb[0];
  for (int j0 = 0; j0 < 24; ++j0) {
    const float4 h4 = *(const float4*)(hp + j0 * 4);
    acc += h4.x * sW[j0 * 4] + h4.y * sW[j0 * 4 + 1] + h4.z * sW[j0 * 4 + 2] + h4.w * sW[j0 * 4 + 3];
  }
  go[idx] = acc;
  const int n = idx >> 6, b = idx & 63;
  out[((size_t)b * HOR_ + t) * NN + n] = acc;
}

// ---------------------------------------------------------------------------
extern "C" void kernel_launch(void* const* d_in, const int* in_sizes, int n_in,
                              void* d_out, int out_size, void* d_ws, size_t ws_size,
                              hipStream_t stream) {
  const float* x    = (const float*)d_in[0];
  const float* ycov = (const float*)d_in[1];
  const float* emb  = (const float*)d_in[2];
  const float* egW  = (const float*)d_in[3];
  const float* egb  = (const float*)d_in[4];
  const float* euW  = (const float*)d_in[5];
  const float* eub  = (const float*)d_in[6];
  const float* Mem  = (const float*)d_in[7];
  const float* Wq   = (const float*)d_in[8];
  const float* FCE  = (const float*)d_in[9];
  const float* dgW  = (const float*)d_in[10];
  const float* dgb  = (const float*)d_in[11];
  const float* duW  = (const float*)d_in[12];
  const float* dub  = (const float*)d_in[13];
  const float* pW   = (const float*)d_in[14];
  const float* pb   = (const float*)d_in[15];
  float* out = (float*)d_out;

  char* w = (char*)d_ws;
  auto alloc = [&](size_t bytes) {
    void* p = (void*)w;
    w += (bytes + 255) & ~(size_t)255;
    return p;
  };
  float* S1  = (float*)alloc((size_t)NN * NN * 4);
  float* zr  = (float*)alloc((size_t)NN * B_ * 192 * 4);
  float* hA  = (float*)alloc((size_t)NN * B_ * 64 * 4);
  float* hB  = (float*)alloc((size_t)NN * B_ * 96 * 4);
  float* go  = (float*)alloc((size_t)NN * B_ * 4);
  float* WE  = (float*)alloc((size_t)NN * B_ * 8 * 4);
  ushort_t* S1h = (ushort_t*)alloc((size_t)NN * NN * 2);
  ushort_t* S1l = (ushort_t*)alloc((size_t)NN * NN * 2);
  ushort_t* S2h = (ushort_t*)alloc((size_t)NN * NN * 2);
  ushort_t* S2l = (ushort_t*)alloc((size_t)NN * NN * 2);
  ushort_t* XTh = (ushort_t*)alloc((size_t)B_ * 98 * NN * 2);
  ushort_t* XTl = (ushort_t*)alloc((size_t)B_ * 98 * NN * 2);
  ushort_t* Agh = (ushort_t*)alloc((size_t)NN * B_ * 320 * 2);
  ushort_t* Agl = (ushort_t*)alloc((size_t)NN * B_ * 320 * 2);
  ushort_t* WtegH = (ushort_t*)alloc(128 * 224 * 2);
  ushort_t* WtegL = (ushort_t*)alloc(128 * 224 * 2);
  ushort_t* WteuH = (ushort_t*)alloc(64 * 224 * 2);
  ushort_t* WteuL = (ushort_t*)alloc(64 * 224 * 2);
  ushort_t* WtdgH = (ushort_t*)alloc(192 * 320 * 2);
  ushort_t* WtdgL = (ushort_t*)alloc(192 * 320 * 2);
  ushort_t* WtduH = (ushort_t*)alloc(128 * 320 * 2);
  ushort_t* WtduL = (ushort_t*)alloc(128 * 320 * 2);
  (void)ws_size; (void)in_sizes; (void)n_in; (void)out_size;

  const dim3 blk(256);

  // ---- weight transposes + buffer init (pad regions must be defined) ----
  wt_kernel<<<(128 * 224 + 255) / 256, blk, 0, stream>>>(egW, WtegH, WtegL, 195, 128, 224, 128);
  wt_kernel<<<(64 * 224 + 255) / 256, blk, 0, stream>>>(euW, WteuH, WteuL, 195, 64, 224, 64);
  wt_kernel<<<(192 * 320 + 255) / 256, blk, 0, stream>>>(dgW, WtdgH, WtdgL, 294, 192, 320, 192);
  wt_kernel<<<(128 * 320 + 255) / 256, blk, 0, stream>>>(duW, WtduH, WtduL, 294, 96, 320, 128);
  hipMemsetAsync(Agh, 0, (size_t)NN * B_ * 320 * 2, stream);
  hipMemsetAsync(Agl, 0, (size_t)NN * B_ * 320 * 2, stream);
  hipMemsetAsync(hA, 0, (size_t)NN * B_ * 64 * 4, stream);
  hipMemsetAsync(go, 0, (size_t)NN * B_ * 4, stream);

  // ---- encoder supports ----
  gemm_nt_kernel<<<dim3(16, 16), blk, 0, stream>>>(emb, emb, S1, NN, 8);
  relu_softmax_kernel<<<NN, blk, 0, stream>>>(S1, S1h, S1l);
  cheb_kernel<<<dim3(16, 16), blk, 0, stream>>>(S1, S2h, S2l);

  // ---- encoder scan ----  (W_enc = 4160; graph grid 33*128 = 4224 padded)
  for (int t = 0; t < T_; ++t) {
    prep_kernel<65, 224, 0><<<dim3(65, 16), blk, 0, stream>>>(x, nullptr, hA, nullptr, Agh, Agl, XTh, XTl, t);
    graph_mfma_kernel<65, 224><<<dim3(33, 16), blk, 0, stream>>>(S1h, S1l, S2h, S2l, XTh, XTl, Agh, Agl);
    dense_mfma_kernel<224, 128, 128, 0, 64><<<512, blk, 0, stream>>>(Agh, Agl, WtegH, WtegL, egb, zr, nullptr);
    prep_kernel<65, 224, 1><<<dim3(65, 16), blk, 0, stream>>>(x, nullptr, hA, zr, Agh, Agl, XTh, XTl, t);
    graph_mfma_kernel<65, 224><<<dim3(33, 16), blk, 0, stream>>>(S1h, S1l, S2h, S2l, XTh, XTl, Agh, Agl);
    dense_mfma_kernel<224, 64, 64, 1, 64><<<512, blk, 0, stream>>>(Agh, Agl, WteuH, WteuL, eub, hA, zr);
  }

  // ---- attention / memory / decoder supports ----
  attn_kernel<<<256, blk, 0, stream>>>(hA, Wq, Mem, FCE, hB, WE);
  gemm_nt_kernel<<<dim3(16, 16), blk, 0, stream>>>(WE, WE, S1, NN, 512);
  relu_softmax_kernel<<<NN, blk, 0, stream>>>(S1, S1h, S1l);
  cheb_kernel<<<dim3(16, 16), blk, 0, stream>>>(S1, S2h, S2l);

  // ---- decoder scan ----  (W_dec = 6272 = 49*128 exactly)
  for (int t = 0; t < HOR_; ++t) {
    prep_kernel<98, 320, 2><<<dim3(98, 16), blk, 0, stream>>>(go, ycov, hB, nullptr, Agh, Agl, XTh, XTl, t);
    graph_mfma_kernel<98, 320><<<dim3(49, 16), blk, 0, stream>>>(S1h, S1l, S2h, S2l, XTh, XTl, Agh, Agl);
    dense_mfma_kernel<320, 192, 192, 0, 96><<<512, blk, 0, stream>>>(Agh, Agl, WtdgH, WtdgL, dgb, zr, nullptr);
    prep_kernel<98, 320, 3><<<dim3(98, 16), blk, 0, stream>>>(go, ycov, hB, zr, Agh, Agl, XTh, XTl, t);
    graph_mfma_kernel<98, 320><<<dim3(49, 16), blk, 0, stream>>>(S1h, S1l, S2h, S2l, XTh, XTl, Agh, Agl);
    dense_mfma_kernel<320, 96, 128, 1, 96><<<512, blk, 0, stream>>>(Agh, Agl, WtduH, WtduL, dub, hB, zr);
    proj_kernel<<<256, blk, 0, stream>>>(hB, pW, pb, go, out, t);
  }
}